// Round 1
// 850.752 us; speedup vs baseline: 1.0660x; 1.0660x over previous
//
#include <hip/hip_runtime.h>

#define NUu 500000
#define NIi 100000
#define FDIM 300
#define DDIM 64
#define NEe 2000000
#define ELl 1000000
#define EMAX (NEe - 1)

// bucket config for CSR build
#define BSZL_I 8      // 256 items per bucket
#define BSZL_U 9      // 512 users per bucket
#define NB_I 391      // ceil(NIi/256)
#define NB_U 977      // ceil(NUu/512)
#define NBT (NB_I + NB_U)   // 1368
#define SH_I 19       // src < 2^19 packed low, d_local<<19
#define SH_U 17       // dst < 2^17 packed low, s_local<<17

typedef __attribute__((ext_vector_type(8))) short s8v;
typedef __attribute__((ext_vector_type(4))) short s4v;
typedef __attribute__((ext_vector_type(4))) float f4v;
typedef unsigned short u16;

__device__ __forceinline__ float bf2f(u16 h) {
    union { unsigned u; float f; } x; x.u = ((unsigned)h) << 16; return x.f;
}
__device__ __forceinline__ u16 f2bf(float f) {
    union { float f; unsigned u; } x; x.f = f;
    unsigned u = x.u;
    u += 0x7FFFu + ((u >> 16) & 1u);   // round-to-nearest-even
    return (u16)(u >> 16);
}

// ---------------- cast user embeddings (with user_node_id gather) to bf16 ----
__global__ __launch_bounds__(256) void k_cast_users(const float* __restrict__ ue,
                                                    const int* __restrict__ uid,
                                                    u16* __restrict__ xu) {
    int idx = blockIdx.x * 256 + threadIdx.x;   // one thread = 4 elems
    int n  = idx >> 4;
    int d0 = (idx & 15) * 4;
    int src = uid[n];
    const float4* p = (const float4*)(ue + (size_t)src * DDIM + d0);
    float4 v = *p;
    s4v o;
    o[0] = (short)f2bf(v.x); o[1] = (short)f2bf(v.y);
    o[2] = (short)f2bf(v.z); o[3] = (short)f2bf(v.w);
    *(s4v*)(xu + (size_t)n * DDIM + d0) = o;
}

// ---------------- cast item_lin_w to bf16 in MFMA B-fragment order ----------
__global__ __launch_bounds__(256) void k_cast_w(const float* __restrict__ W,
                                                u16* __restrict__ wbf) {
    int idx = blockIdx.x * 256 + threadIdx.x;   // 2560 lane-slots
    if (idx >= 2560) return;
    int f = idx >> 6, lane = idx & 63;
    int q = lane >> 4, c = lane & 15;
    int kstep = f >> 2, nb = f & 3;
    u16* dst = wbf + (size_t)idx * 8;
#pragma unroll
    for (int j = 0; j < 8; j++) {
        int k = kstep * 32 + q * 8 + j;
        float v = (k < FDIM) ? W[k * DDIM + nb * 16 + c] : 0.f;
        dst[j] = f2bf(v);
    }
}

// ---------------- cast the 8 SAGE weight matrices to B-fragment order --------
// blob layout (u16 elems): wm*4096 + ks*2048 + nb*512 + lane*8 + j
// wm = 2*tix + which  (which: 0=Wl, 1=Wr), tix = transform index 0..3
__global__ __launch_bounds__(256) void k_cast_w8(
    const float* __restrict__ W0, const float* __restrict__ W1,
    const float* __restrict__ W2, const float* __restrict__ W3,
    const float* __restrict__ W4, const float* __restrict__ W5,
    const float* __restrict__ W6, const float* __restrict__ W7,
    u16* __restrict__ out) {
    int idx = blockIdx.x * 256 + threadIdx.x;   // 4096 slots
    if (idx >= 4096) return;
    int wm = idx >> 9;        // uniform per block (block = 256 slots)
    int s = idx & 511;
    int ks = s >> 8, nb = (s >> 6) & 3, lane = s & 63;
    int q = lane >> 4, c = lane & 15;
    const float* W;
    switch (wm) {
        case 0: W = W0; break; case 1: W = W1; break;
        case 2: W = W2; break; case 3: W = W3; break;
        case 4: W = W4; break; case 5: W = W5; break;
        case 6: W = W6; break; default: W = W7; break;
    }
    u16* dst = out + (size_t)idx * 8;
#pragma unroll
    for (int j = 0; j < 8; j++) {
        int row = ks * 32 + q * 8 + j;
        dst[j] = f2bf(W[row * DDIM + nb * 16 + c]);
    }
}

// ---------------- item linear via MFMA: xi = item_x @ W + b ------------------
__global__ __launch_bounds__(256) void k_item_lin2(const float* __restrict__ ix,
                                                   const u16* __restrict__ wbf,
                                                   const float* __restrict__ b,
                                                   u16* __restrict__ xi) {
    __shared__ __align__(16) u16 wl[40 * 64 * 8];   // 40960 B
    int tid = threadIdx.x;
    for (int i = tid; i < 2560; i += 256)
        ((f4v*)wl)[i] = ((const f4v*)wbf)[i];
    __syncthreads();

    int lane = tid & 63;
    int q = lane >> 4, c = lane & 15;
    float bv[4];
#pragma unroll
    for (int nb = 0; nb < 4; nb++) bv[nb] = b[nb * 16 + c];

    int w = blockIdx.x * 4 + (tid >> 6);
    int stride = gridDim.x * 4;
    const int NT = NIi / 16;   // 6250
    for (int t = w; t < NT; t += stride) {
        int row = t * 16 + c;
        const float* xr = ix + (size_t)row * FDIM;
        f4v acc[4];
#pragma unroll
        for (int nb = 0; nb < 4; nb++) {
            acc[nb][0] = bv[nb]; acc[nb][1] = bv[nb];
            acc[nb][2] = bv[nb]; acc[nb][3] = bv[nb];
        }
#pragma unroll
        for (int ks = 0; ks < 10; ks++) {
            s8v a;
            if (ks < 9 || q == 0) {
                float4 v0 = *(const float4*)(xr + ks * 32 + q * 8);
                float4 v1 = *(const float4*)(xr + ks * 32 + q * 8 + 4);
                a[0] = (short)f2bf(v0.x); a[1] = (short)f2bf(v0.y);
                a[2] = (short)f2bf(v0.z); a[3] = (short)f2bf(v0.w);
                a[4] = (short)f2bf(v1.x); a[5] = (short)f2bf(v1.y);
                a[6] = (short)f2bf(v1.z); a[7] = (short)f2bf(v1.w);
            } else {   // ks==9, q==1: k = 296..303, valid only 296..299
                float4 v0 = *(const float4*)(xr + 296);
                a[0] = (short)f2bf(v0.x); a[1] = (short)f2bf(v0.y);
                a[2] = (short)f2bf(v0.z); a[3] = (short)f2bf(v0.w);
                a[4] = 0; a[5] = 0; a[6] = 0; a[7] = 0;
            }
#pragma unroll
            for (int nb = 0; nb < 4; nb++) {
                s8v bb = *(const s8v*)(wl + ((size_t)(ks * 4 + nb) * 64 + lane) * 8);
                acc[nb] = __builtin_amdgcn_mfma_f32_16x16x32_bf16(a, bb, acc[nb], 0, 0, 0);
            }
        }
#pragma unroll
        for (int nb = 0; nb < 4; nb++)
#pragma unroll
            for (int r = 0; r < 4; r++)
                xi[(size_t)(t * 16 + q * 4 + r) * DDIM + nb * 16 + c] = f2bf(acc[nb][r]);
    }
}

// ---------------- CSR build: bucketed multisplit ------------------------------
__global__ __launch_bounds__(256) void k_hist(const int* __restrict__ src,
                                              const int* __restrict__ dst,
                                              int* __restrict__ hist) {
    __shared__ int h[NBT];
    int t = threadIdx.x;
    for (int c = t; c < NBT; c += 256) h[c] = 0;
    __syncthreads();
    int base = blockIdx.x * 2048;
#pragma unroll
    for (int k = 0; k < 8; k++) {
        int e = base + k * 256 + t;
        if (e < NEe) {
            int s = src[e], d = dst[e];
            atomicAdd(&h[d >> BSZL_I], 1);
            atomicAdd(&h[NB_I + (s >> BSZL_U)], 1);
        }
    }
    __syncthreads();
    for (int c = t; c < NBT; c += 256) {
        int n = h[c];
        if (n) atomicAdd(&hist[c], n);
    }
}

__device__ __forceinline__ void scanN(const int* __restrict__ cnt, int n, int total,
                                      int* __restrict__ base, int* __restrict__ frontier,
                                      int* sb) {
    int t = threadIdx.x;
    int v[8]; int s = 0;
#pragma unroll
    for (int i = 0; i < 8; i++) {
        int idx = t * 8 + i;
        v[i] = (idx < n) ? cnt[idx] : 0;
        s += v[i];
    }
    sb[t] = s; __syncthreads();
    for (int o = 1; o < 256; o <<= 1) {
        int a = (t >= o) ? sb[t - o] : 0;
        __syncthreads();
        sb[t] += a;
        __syncthreads();
    }
    int run = sb[t] - s;
#pragma unroll
    for (int i = 0; i < 8; i++) {
        int idx = t * 8 + i;
        if (idx < n) { base[idx] = run; frontier[idx] = run; }
        run += v[i];
    }
    if (t == 0) base[n] = total;
    __syncthreads();
}

__global__ __launch_bounds__(256) void k_bucket_scan(const int* __restrict__ hist,
                                                     int* __restrict__ base_i, int* __restrict__ fr_i,
                                                     int* __restrict__ base_u, int* __restrict__ fr_u,
                                                     int* __restrict__ rpi, int* __restrict__ rpu) {
    __shared__ int sb[256];
    scanN(hist, NB_I, NEe, base_i, fr_i, sb);
    scanN(hist + NB_I, NB_U, NEe, base_u, fr_u, sb);
    if (threadIdx.x == 0) { rpi[NIi] = NEe; rpu[NUu] = NEe; }
}

__global__ __launch_bounds__(256) void k_scatter(const int* __restrict__ src,
                                                 const int* __restrict__ dst,
                                                 int* __restrict__ fr_i, int* __restrict__ fr_u,
                                                 unsigned* __restrict__ scat_i,
                                                 unsigned* __restrict__ scat_u) {
    __shared__ int h[NBT];
    int t = threadIdx.x;
    for (int c = t; c < NBT; c += 256) h[c] = 0;
    __syncthreads();
    int base = blockIdx.x * 2048;
#pragma unroll
    for (int k = 0; k < 8; k++) {
        int e = base + k * 256 + t;
        if (e < NEe) {
            int s = src[e], d = dst[e];
            atomicAdd(&h[d >> BSZL_I], 1);
            atomicAdd(&h[NB_I + (s >> BSZL_U)], 1);
        }
    }
    __syncthreads();
    for (int c = t; c < NBT; c += 256) {
        int n = h[c];
        if (n) {
            int b = (c < NB_I) ? atomicAdd(&fr_i[c], n) : atomicAdd(&fr_u[c - NB_I], n);
            h[c] = b;
        }
    }
    __syncthreads();
#pragma unroll
    for (int k = 0; k < 8; k++) {
        int e = base + k * 256 + t;
        if (e < NEe) {
            int s = src[e], d = dst[e];
            int p = atomicAdd(&h[d >> BSZL_I], 1);
            scat_i[p] = (unsigned)s | ((unsigned)(d & 255) << SH_I);
            int q = atomicAdd(&h[NB_I + (s >> BSZL_U)], 1);
            scat_u[q] = (unsigned)d | ((unsigned)(s & 511) << SH_U);
        }
    }
}

__global__ __launch_bounds__(256) void k_bfill(const unsigned* __restrict__ scat,
                                               const int* __restrict__ base,
                                               int* __restrict__ rp, int* __restrict__ col,
                                               int shift, int bszlog, int ntotal) {
    __shared__ int cnt[512];
    __shared__ int pos[512];
    __shared__ int sb[256];
    int b = blockIdx.x;
    int t = threadIdx.x;
    int e0 = base[b], e1 = base[b + 1];
    int node0 = b << bszlog;
    int bsz = 1 << bszlog;
    unsigned mask = (1u << shift) - 1u;

    for (int c = t; c < bsz; c += 256) cnt[c] = 0;
    __syncthreads();
    for (int e = e0 + t; e < e1; e += 256) {
        unsigned v = scat[e];
        atomicAdd(&cnt[v >> shift], 1);
    }
    __syncthreads();
    int per = bsz >> 8;
    int loc[2]; int ls = 0;
#pragma unroll
    for (int i = 0; i < 2; i++) {
        loc[i] = (i < per) ? cnt[t * per + i] : 0;
        ls += loc[i];
    }
    sb[t] = ls; __syncthreads();
    for (int o = 1; o < 256; o <<= 1) {
        int a = (t >= o) ? sb[t - o] : 0;
        __syncthreads();
        sb[t] += a;
        __syncthreads();
    }
    int run = e0 + sb[t] - ls;
#pragma unroll
    for (int i = 0; i < 2; i++) {
        if (i < per) {
            int idx = t * per + i;
            int node = node0 + idx;
            if (node < ntotal) rp[node] = run;
            pos[idx] = run;
            run += loc[i];
        }
    }
    __syncthreads();
    for (int e = e0 + t; e < e1; e += 256) {
        unsigned v = scat[e];
        int l = v >> shift;
        int p = atomicAdd(&pos[l], 1);
        col[p] = (int)(v & mask);
    }
}

// ---------------- fused mean-agg + SAGE transform ----------------------------
// out[tile] = [relu]( mean_agg(feat) @ Wl + x @ Wr + b )
// lane (q,c): node = t*16+c, accumulates dims {q*8..q*8+7} and {32+q*8..} in f32
// -> accumulator IS the MFMA A-fragment (a0 = k 0..31, a1 = k 32..63).
// Weights staged in LDS (B-fragment order from k_cast_w8), re-read per tile
// through a laundered offset so they stay in LDS (keeps VGPR low for occupancy).
__global__ __launch_bounds__(256) void k_fused(const u16* __restrict__ feat,
                                               const u16* __restrict__ xf,
                                               const u16* __restrict__ wfrag,
                                               const float* __restrict__ bias,
                                               u16* __restrict__ out,
                                               const int* __restrict__ rp,
                                               const int* __restrict__ col,
                                               int ntiles, int relu) {
    __shared__ __align__(16) u16 wsh[8192];   // 16 KB: [which][ks][nb][lane][8]
    int tid = threadIdx.x;
    for (int i = tid; i < 1024; i += 256)
        ((f4v*)wsh)[i] = ((const f4v*)wfrag)[i];
    __syncthreads();

    int lane = tid & 63;
    int q = lane >> 4, c = lane & 15;
    int w = blockIdx.x * 4 + (tid >> 6);
    int stride = gridDim.x * 4;
    float bv[4];
#pragma unroll
    for (int nb = 0; nb < 4; nb++) bv[nb] = bias[nb * 16 + c];

    for (int t = w; t < ntiles; t += stride) {
        int node = t * 16 + c;
        int s0 = rp[node], s1 = rp[node + 1];
        int deg = s1 - s0;
        float inv = (deg > 0) ? 1.0f / (float)deg : 0.0f;

        // self fragment: issue early, consumed after agg loop (latency hidden)
        const s8v* px = (const s8v*)(xf + (size_t)node * DDIM + q * 8);
        s8v x0 = px[0], x1 = px[4];

        float accA[8] = {0.f, 0.f, 0.f, 0.f, 0.f, 0.f, 0.f, 0.f};
        float accB[8] = {0.f, 0.f, 0.f, 0.f, 0.f, 0.f, 0.f, 0.f};

        // maskless 2-edge-unrolled gather loop: 16 independent node chains/wave,
        // inactive lanes read a clamped (coalesced, cached) dummy edge with mask 0
        for (int i = 0; __any(i < deg); i += 2) {
            int ia = s0 + i;
            int ea = min(ia, EMAX);
            int eb = min(ia + 1, EMAX);
            int ra = col[ea];
            int rb = col[eb];
            float ma = (i < deg) ? inv : 0.f;       // fold 1/deg into mask
            float mb = (i + 1 < deg) ? inv : 0.f;
            const u16* fa = feat + (size_t)ra * DDIM + q * 8;
            const u16* fb = feat + (size_t)rb * DDIM + q * 8;
            s8v va0 = *(const s8v*)fa;
            s8v va1 = *(const s8v*)(fa + 32);
            s8v vb0 = *(const s8v*)fb;
            s8v vb1 = *(const s8v*)(fb + 32);
#pragma unroll
            for (int j = 0; j < 8; j++) {
                accA[j] = fmaf(ma, bf2f((u16)va0[j]), accA[j]);
                accB[j] = fmaf(ma, bf2f((u16)va1[j]), accB[j]);
                accA[j] = fmaf(mb, bf2f((u16)vb0[j]), accA[j]);
                accB[j] = fmaf(mb, bf2f((u16)vb1[j]), accB[j]);
            }
        }

        // mean is already scaled; convert to A-fragments
        s8v a0, a1;
#pragma unroll
        for (int j = 0; j < 8; j++) {
            a0[j] = (short)f2bf(accA[j]);
            a1[j] = (short)f2bf(accB[j]);
        }

        f4v acc[4];
#pragma unroll
        for (int nb = 0; nb < 4; nb++) {
            acc[nb][0] = bv[nb]; acc[nb][1] = bv[nb];
            acc[nb][2] = bv[nb]; acc[nb][3] = bv[nb];
        }

        // launder the LDS offset each tile so the 16 weight ds_reads are NOT
        // hoisted out of the loop into 64 VGPRs (occupancy protection)
        unsigned lz = (unsigned)lane * 8u;
        asm volatile("" : "+v"(lz));
        const u16* wb = wsh + lz;
#pragma unroll
        for (int nb = 0; nb < 4; nb++) {
            s8v wl0 = *(const s8v*)(wb + nb * 512);            // Wl ks=0
            s8v wl1 = *(const s8v*)(wb + 2048 + nb * 512);     // Wl ks=1
            s8v wr0 = *(const s8v*)(wb + 4096 + nb * 512);     // Wr ks=0
            s8v wr1 = *(const s8v*)(wb + 6144 + nb * 512);     // Wr ks=1
            acc[nb] = __builtin_amdgcn_mfma_f32_16x16x32_bf16(a0, wl0, acc[nb], 0, 0, 0);
            acc[nb] = __builtin_amdgcn_mfma_f32_16x16x32_bf16(a1, wl1, acc[nb], 0, 0, 0);
            acc[nb] = __builtin_amdgcn_mfma_f32_16x16x32_bf16(x0, wr0, acc[nb], 0, 0, 0);
            acc[nb] = __builtin_amdgcn_mfma_f32_16x16x32_bf16(x1, wr1, acc[nb], 0, 0, 0);
        }
#pragma unroll
        for (int nb = 0; nb < 4; nb++)
#pragma unroll
            for (int r = 0; r < 4; r++) {
                float v = acc[nb][r];
                if (relu) v = fmaxf(v, 0.f);
                out[(size_t)(t * 16 + q * 4 + r) * DDIM + nb * 16 + c] = f2bf(v);
            }
    }
}

// ---------------- final dot predictor (8 edges per wave, 16 B/lane) ----------
__global__ __launch_bounds__(256) void k_dot(const u16* __restrict__ hu,
                                             const u16* __restrict__ hi,
                                             const int* __restrict__ ls,
                                             const int* __restrict__ ld,
                                             float* __restrict__ out) {
    int lane = threadIdx.x & 63;
    int sub = lane >> 3, t8 = lane & 7;
    int w = blockIdx.x * 4 + (threadIdx.x >> 6);
    int stride = gridDim.x * 4;
    const int ngroups = ELl / 8;
    for (int g = w; g < ngroups; g += stride) {
        int e = g * 8 + sub;
        int u = ls[e], it = ld[e];
        s8v av = *(const s8v*)(hu + (size_t)u  * DDIM + t8 * 8);
        s8v bv = *(const s8v*)(hi + (size_t)it * DDIM + t8 * 8);
        float s = 0.f;
#pragma unroll
        for (int k = 0; k < 8; k++) s += bf2f((u16)av[k]) * bf2f((u16)bv[k]);
        s += __shfl_xor(s, 4);
        s += __shfl_xor(s, 2);
        s += __shfl_xor(s, 1);
        if (t8 == 0) out[e] = s;
    }
}

extern "C" void kernel_launch(void* const* d_in, const int* in_sizes, int n_in,
                              void* d_out, int out_size, void* d_ws, size_t ws_size,
                              hipStream_t stream) {
    const float* user_emb = (const float*)d_in[0];
    const float* item_x   = (const float*)d_in[1];
    const float* item_w   = (const float*)d_in[2];
    const float* item_b   = (const float*)d_in[3];
    const float* Wl1_ui = (const float*)d_in[4];
    const float* Wr1_ui = (const float*)d_in[5];
    const float* b1_ui  = (const float*)d_in[6];
    const float* Wl1_iu = (const float*)d_in[7];
    const float* Wr1_iu = (const float*)d_in[8];
    const float* b1_iu  = (const float*)d_in[9];
    const float* Wl2_ui = (const float*)d_in[10];
    const float* Wr2_ui = (const float*)d_in[11];
    const float* b2_ui  = (const float*)d_in[12];
    const float* Wl2_iu = (const float*)d_in[13];
    const float* Wr2_iu = (const float*)d_in[14];
    const float* b2_iu  = (const float*)d_in[15];
    const int* uid  = (const int*)d_in[16];
    const int* esrc = (const int*)d_in[17];
    const int* edst = (const int*)d_in[18];
    const int* lsrc = (const int*)d_in[19];
    const int* ldst = (const int*)d_in[20];
    float* out = (float*)d_out;

    char* ws = (char*)d_ws;
    size_t off = 0;
    auto alloc = [&](size_t bytes) -> void* {
        void* p = ws + off;
        off += (bytes + 255) & ~(size_t)255;
        return p;
    };
    u16* xu_b   = (u16*)alloc((size_t)NUu * DDIM * 2);
    u16* hu1_b  = (u16*)alloc((size_t)NUu * DDIM * 2);
    u16* hu2_b  = (u16*)alloc((size_t)NUu * DDIM * 2);
    u16* xi_b   = (u16*)alloc((size_t)NIi * DDIM * 2);
    u16* hi1_b  = (u16*)alloc((size_t)NIi * DDIM * 2);
    u16* hi2_b  = (u16*)alloc((size_t)NIi * DDIM * 2);
    int* coli = (int*)alloc((size_t)NEe * 4);
    int* colu = (int*)alloc((size_t)NEe * 4);
    int* rpi  = (int*)alloc((size_t)(NIi + 1) * 4);
    int* rpu  = (int*)alloc((size_t)(NUu + 1) * 4);
    int* hist   = (int*)alloc((size_t)NBT * 4);
    int* base_i = (int*)alloc((size_t)(NB_I + 1) * 4);
    int* base_u = (int*)alloc((size_t)(NB_U + 1) * 4);
    int* fr_i   = (int*)alloc((size_t)NB_I * 4);
    int* fr_u   = (int*)alloc((size_t)NB_U * 4);
    u16* wbf    = (u16*)alloc((size_t)40 * 64 * 8 * 2);   // item W, frag order
    u16* wfrag2 = (u16*)alloc((size_t)4 * 8192 * 2);      // 4 transforms x 16 KB
    // scatter buffers alias xu_b (16 MB < 64 MB): CSR build runs before k_cast_users
    unsigned* scat_i = (unsigned*)xu_b;
    unsigned* scat_u = (unsigned*)((char*)xu_b + (size_t)NEe * 4);

    // ---- CSR build (bucketed) ----
    hipMemsetAsync(hist, 0, (size_t)NBT * 4, stream);
    int nchunks = (NEe + 2047) / 2048;   // 977
    k_hist<<<nchunks, 256, 0, stream>>>(esrc, edst, hist);
    k_bucket_scan<<<1, 256, 0, stream>>>(hist, base_i, fr_i, base_u, fr_u, rpi, rpu);
    k_scatter<<<nchunks, 256, 0, stream>>>(esrc, edst, fr_i, fr_u, scat_i, scat_u);
    k_bfill<<<NB_I, 256, 0, stream>>>(scat_i, base_i, rpi, coli, SH_I, BSZL_I, NIi);
    k_bfill<<<NB_U, 256, 0, stream>>>(scat_u, base_u, rpu, colu, SH_U, BSZL_U, NUu);

    // ---- input features (after CSR build: scat_* alias xu_b) ----
    k_cast_w<<<10, 256, 0, stream>>>(item_w, wbf);
    k_cast_w8<<<16, 256, 0, stream>>>(Wl1_ui, Wr1_ui, Wl1_iu, Wr1_iu,
                                      Wl2_ui, Wr2_ui, Wl2_iu, Wr2_iu, wfrag2);
    k_cast_users<<<NUu * 16 / 256, 256, 0, stream>>>(user_emb, uid, xu_b);
    k_item_lin2<<<512, 256, 0, stream>>>(item_x, wbf, item_b, xi_b);

    const int NT_I = NIi / 16;   // 6250
    const int NT_U = NUu / 16;   // 31250

    // layer 1 (fused agg + transform)
    k_fused<<<512, 256, 0, stream>>>(xu_b, xi_b, wfrag2 + 0 * 8192, b1_ui,
                                     hi1_b, rpi, coli, NT_I, 1);
    k_fused<<<2048, 256, 0, stream>>>(xi_b, xu_b, wfrag2 + 1 * 8192, b1_iu,
                                      hu1_b, rpu, colu, NT_U, 1);
    // layer 2
    k_fused<<<512, 256, 0, stream>>>(hu1_b, hi1_b, wfrag2 + 2 * 8192, b2_ui,
                                     hi2_b, rpi, coli, NT_I, 0);
    k_fused<<<2048, 256, 0, stream>>>(hi1_b, hu1_b, wfrag2 + 3 * 8192, b2_iu,
                                      hu2_b, rpu, colu, NT_U, 0);

    // predictor
    k_dot<<<2048, 256, 0, stream>>>(hu2_b, hi2_b, lsrc, ldst, out);
}

// Round 3
// 813.484 us; speedup vs baseline: 1.1148x; 1.0458x over previous
//
#include <hip/hip_runtime.h>

#define NUu 500000
#define NIi 100000
#define FDIM 300
#define DDIM 64
#define NEe 2000000
#define ELl 1000000
#define EMAX (NEe - 1)

// bucket config for CSR build
#define BSZL_I 8      // 256 items per bucket
#define BSZL_U 9      // 512 users per bucket
#define NB_I 391      // ceil(NIi/256)
#define NB_U 977      // ceil(NUu/512)
#define NBT (NB_I + NB_U)   // 1368
#define SH_I 19       // src < 2^19 packed low, d_local<<19
#define SH_U 17       // dst < 2^17 packed low, s_local<<17

#define DBINS 64      // degree-sort bins (clamped)

typedef __attribute__((ext_vector_type(8))) short s8v;
typedef __attribute__((ext_vector_type(4))) short s4v;
typedef __attribute__((ext_vector_type(4))) float f4v;
typedef __attribute__((ext_vector_type(4))) unsigned u4v;
typedef unsigned short u16;

__device__ __forceinline__ float bf2f(u16 h) {
    union { unsigned u; float f; } x; x.u = ((unsigned)h) << 16; return x.f;
}
__device__ __forceinline__ u16 f2bf(float f) {
    union { float f; unsigned u; } x; x.f = f;
    unsigned u = x.u;
    u += 0x7FFFu + ((u >> 16) & 1u);   // round-to-nearest-even
    return (u16)(u >> 16);
}
__device__ __forceinline__ float lo2f(unsigned u) {
    union { unsigned x; float f; } c; c.x = u << 16; return c.f;
}
__device__ __forceinline__ float hi2f(unsigned u) {
    union { unsigned x; float f; } c; c.x = u & 0xffff0000u; return c.f;
}

// ---------------- cast user embeddings (with user_node_id gather) to bf16 ----
__global__ __launch_bounds__(256) void k_cast_users(const float* __restrict__ ue,
                                                    const int* __restrict__ uid,
                                                    u16* __restrict__ xu) {
    int idx = blockIdx.x * 256 + threadIdx.x;   // one thread = 4 elems
    int n  = idx >> 4;
    int d0 = (idx & 15) * 4;
    int src = uid[n];
    const float4* p = (const float4*)(ue + (size_t)src * DDIM + d0);
    float4 v = *p;
    s4v o;
    o[0] = (short)f2bf(v.x); o[1] = (short)f2bf(v.y);
    o[2] = (short)f2bf(v.z); o[3] = (short)f2bf(v.w);
    *(s4v*)(xu + (size_t)n * DDIM + d0) = o;
}

// ---------------- cast item_lin_w to bf16 in MFMA B-fragment order ----------
__global__ __launch_bounds__(256) void k_cast_w(const float* __restrict__ W,
                                                u16* __restrict__ wbf) {
    int idx = blockIdx.x * 256 + threadIdx.x;   // 2560 lane-slots
    if (idx >= 2560) return;
    int f = idx >> 6, lane = idx & 63;
    int q = lane >> 4, c = lane & 15;
    int kstep = f >> 2, nb = f & 3;
    u16* dst = wbf + (size_t)idx * 8;
#pragma unroll
    for (int j = 0; j < 8; j++) {
        int k = kstep * 32 + q * 8 + j;
        float v = (k < FDIM) ? W[k * DDIM + nb * 16 + c] : 0.f;
        dst[j] = f2bf(v);
    }
}

// ---------------- cast the 8 SAGE weight matrices to B-fragment order --------
__global__ __launch_bounds__(256) void k_cast_w8(
    const float* __restrict__ W0, const float* __restrict__ W1,
    const float* __restrict__ W2, const float* __restrict__ W3,
    const float* __restrict__ W4, const float* __restrict__ W5,
    const float* __restrict__ W6, const float* __restrict__ W7,
    u16* __restrict__ out) {
    int idx = blockIdx.x * 256 + threadIdx.x;   // 4096 slots
    if (idx >= 4096) return;
    int wm = idx >> 9;
    int s = idx & 511;
    int ks = s >> 8, nb = (s >> 6) & 3, lane = s & 63;
    int q = lane >> 4, c = lane & 15;
    const float* W;
    switch (wm) {
        case 0: W = W0; break; case 1: W = W1; break;
        case 2: W = W2; break; case 3: W = W3; break;
        case 4: W = W4; break; case 5: W = W5; break;
        case 6: W = W6; break; default: W = W7; break;
    }
    u16* dst = out + (size_t)idx * 8;
#pragma unroll
    for (int j = 0; j < 8; j++) {
        int row = ks * 32 + q * 8 + j;
        dst[j] = f2bf(W[row * DDIM + nb * 16 + c]);
    }
}

// ---------------- item linear via MFMA: xi = item_x @ W + b ------------------
__global__ __launch_bounds__(256) void k_item_lin2(const float* __restrict__ ix,
                                                   const u16* __restrict__ wbf,
                                                   const float* __restrict__ b,
                                                   u16* __restrict__ xi) {
    __shared__ __align__(16) u16 wl[40 * 64 * 8];   // 40960 B
    int tid = threadIdx.x;
    for (int i = tid; i < 2560; i += 256)
        ((f4v*)wl)[i] = ((const f4v*)wbf)[i];
    __syncthreads();

    int lane = tid & 63;
    int q = lane >> 4, c = lane & 15;
    float bv[4];
#pragma unroll
    for (int nb = 0; nb < 4; nb++) bv[nb] = b[nb * 16 + c];

    int w = blockIdx.x * 4 + (tid >> 6);
    int stride = gridDim.x * 4;
    const int NT = NIi / 16;   // 6250
    for (int t = w; t < NT; t += stride) {
        int row = t * 16 + c;
        const float* xr = ix + (size_t)row * FDIM;
        f4v acc[4];
#pragma unroll
        for (int nb = 0; nb < 4; nb++) {
            acc[nb][0] = bv[nb]; acc[nb][1] = bv[nb];
            acc[nb][2] = bv[nb]; acc[nb][3] = bv[nb];
        }
#pragma unroll
        for (int ks = 0; ks < 10; ks++) {
            s8v a;
            if (ks < 9 || q == 0) {
                float4 v0 = *(const float4*)(xr + ks * 32 + q * 8);
                float4 v1 = *(const float4*)(xr + ks * 32 + q * 8 + 4);
                a[0] = (short)f2bf(v0.x); a[1] = (short)f2bf(v0.y);
                a[2] = (short)f2bf(v0.z); a[3] = (short)f2bf(v0.w);
                a[4] = (short)f2bf(v1.x); a[5] = (short)f2bf(v1.y);
                a[6] = (short)f2bf(v1.z); a[7] = (short)f2bf(v1.w);
            } else {   // ks==9, q==1: k = 296..303, valid only 296..299
                float4 v0 = *(const float4*)(xr + 296);
                a[0] = (short)f2bf(v0.x); a[1] = (short)f2bf(v0.y);
                a[2] = (short)f2bf(v0.z); a[3] = (short)f2bf(v0.w);
                a[4] = 0; a[5] = 0; a[6] = 0; a[7] = 0;
            }
#pragma unroll
            for (int nb = 0; nb < 4; nb++) {
                s8v bb = *(const s8v*)(wl + ((size_t)(ks * 4 + nb) * 64 + lane) * 8);
                acc[nb] = __builtin_amdgcn_mfma_f32_16x16x32_bf16(a, bb, acc[nb], 0, 0, 0);
            }
        }
#pragma unroll
        for (int nb = 0; nb < 4; nb++)
#pragma unroll
            for (int r = 0; r < 4; r++)
                xi[(size_t)(t * 16 + q * 4 + r) * DDIM + nb * 16 + c] = f2bf(acc[nb][r]);
    }
}

// ---------------- CSR build: bucketed multisplit ------------------------------
__global__ __launch_bounds__(256) void k_hist(const int* __restrict__ src,
                                              const int* __restrict__ dst,
                                              int* __restrict__ hist) {
    __shared__ int h[NBT];
    int t = threadIdx.x;
    for (int c = t; c < NBT; c += 256) h[c] = 0;
    __syncthreads();
    int base = blockIdx.x * 2048;
#pragma unroll
    for (int k = 0; k < 8; k++) {
        int e = base + k * 256 + t;
        if (e < NEe) {
            int s = src[e], d = dst[e];
            atomicAdd(&h[d >> BSZL_I], 1);
            atomicAdd(&h[NB_I + (s >> BSZL_U)], 1);
        }
    }
    __syncthreads();
    for (int c = t; c < NBT; c += 256) {
        int n = h[c];
        if (n) atomicAdd(&hist[c], n);
    }
}

__device__ __forceinline__ void scanN(const int* __restrict__ cnt, int n, int total,
                                      int* __restrict__ base, int* __restrict__ frontier,
                                      int* sb) {
    int t = threadIdx.x;
    int v[8]; int s = 0;
#pragma unroll
    for (int i = 0; i < 8; i++) {
        int idx = t * 8 + i;
        v[i] = (idx < n) ? cnt[idx] : 0;
        s += v[i];
    }
    sb[t] = s; __syncthreads();
    for (int o = 1; o < 256; o <<= 1) {
        int a = (t >= o) ? sb[t - o] : 0;
        __syncthreads();
        sb[t] += a;
        __syncthreads();
    }
    int run = sb[t] - s;
#pragma unroll
    for (int i = 0; i < 8; i++) {
        int idx = t * 8 + i;
        if (idx < n) { base[idx] = run; frontier[idx] = run; }
        run += v[i];
    }
    if (t == 0) base[n] = total;
    __syncthreads();
}

__global__ __launch_bounds__(256) void k_bucket_scan(const int* __restrict__ hist,
                                                     int* __restrict__ base_i, int* __restrict__ fr_i,
                                                     int* __restrict__ base_u, int* __restrict__ fr_u,
                                                     int* __restrict__ rpi, int* __restrict__ rpu) {
    __shared__ int sb[256];
    scanN(hist, NB_I, NEe, base_i, fr_i, sb);
    scanN(hist + NB_I, NB_U, NEe, base_u, fr_u, sb);
    if (threadIdx.x == 0) { rpi[NIi] = NEe; rpu[NUu] = NEe; }
}

__global__ __launch_bounds__(256) void k_scatter(const int* __restrict__ src,
                                                 const int* __restrict__ dst,
                                                 int* __restrict__ fr_i, int* __restrict__ fr_u,
                                                 unsigned* __restrict__ scat_i,
                                                 unsigned* __restrict__ scat_u) {
    __shared__ int h[NBT];
    int t = threadIdx.x;
    for (int c = t; c < NBT; c += 256) h[c] = 0;
    __syncthreads();
    int base = blockIdx.x * 2048;
#pragma unroll
    for (int k = 0; k < 8; k++) {
        int e = base + k * 256 + t;
        if (e < NEe) {
            int s = src[e], d = dst[e];
            atomicAdd(&h[d >> BSZL_I], 1);
            atomicAdd(&h[NB_I + (s >> BSZL_U)], 1);
        }
    }
    __syncthreads();
    for (int c = t; c < NBT; c += 256) {
        int n = h[c];
        if (n) {
            int b = (c < NB_I) ? atomicAdd(&fr_i[c], n) : atomicAdd(&fr_u[c - NB_I], n);
            h[c] = b;
        }
    }
    __syncthreads();
#pragma unroll
    for (int k = 0; k < 8; k++) {
        int e = base + k * 256 + t;
        if (e < NEe) {
            int s = src[e], d = dst[e];
            int p = atomicAdd(&h[d >> BSZL_I], 1);
            scat_i[p] = (unsigned)s | ((unsigned)(d & 255) << SH_I);
            int q = atomicAdd(&h[NB_I + (s >> BSZL_U)], 1);
            scat_u[q] = (unsigned)d | ((unsigned)(s & 511) << SH_U);
        }
    }
}

__global__ __launch_bounds__(256) void k_bfill(const unsigned* __restrict__ scat,
                                               const int* __restrict__ base,
                                               int* __restrict__ rp, int* __restrict__ col,
                                               int shift, int bszlog, int ntotal) {
    __shared__ int cnt[512];
    __shared__ int pos[512];
    __shared__ int sb[256];
    int b = blockIdx.x;
    int t = threadIdx.x;
    int e0 = base[b], e1 = base[b + 1];
    int node0 = b << bszlog;
    int bsz = 1 << bszlog;
    unsigned mask = (1u << shift) - 1u;

    for (int c = t; c < bsz; c += 256) cnt[c] = 0;
    __syncthreads();
    for (int e = e0 + t; e < e1; e += 256) {
        unsigned v = scat[e];
        atomicAdd(&cnt[v >> shift], 1);
    }
    __syncthreads();
    int per = bsz >> 8;
    int loc[2]; int ls = 0;
#pragma unroll
    for (int i = 0; i < 2; i++) {
        loc[i] = (i < per) ? cnt[t * per + i] : 0;
        ls += loc[i];
    }
    sb[t] = ls; __syncthreads();
    for (int o = 1; o < 256; o <<= 1) {
        int a = (t >= o) ? sb[t - o] : 0;
        __syncthreads();
        sb[t] += a;
        __syncthreads();
    }
    int run = e0 + sb[t] - ls;
#pragma unroll
    for (int i = 0; i < 2; i++) {
        if (i < per) {
            int idx = t * per + i;
            int node = node0 + idx;
            if (node < ntotal) rp[node] = run;
            pos[idx] = run;
            run += loc[i];
        }
    }
    __syncthreads();
    for (int e = e0 + t; e < e1; e += 256) {
        unsigned v = scat[e];
        int l = v >> shift;
        int p = atomicAdd(&pos[l], 1);
        col[p] = (int)(v & mask);
    }
}

// ---------------- degree counting-sort (64 bins) -----------------------------
__global__ __launch_bounds__(256) void k_dhist(const int* __restrict__ rp,
                                               int* __restrict__ hist, int n) {
    __shared__ int h[DBINS];
    int t = threadIdx.x;
    if (t < DBINS) h[t] = 0;
    __syncthreads();
    int base = blockIdx.x * 2048;
#pragma unroll
    for (int k = 0; k < 8; k++) {
        int i = base + k * 256 + t;
        if (i < n) {
            int d = rp[i + 1] - rp[i];
            atomicAdd(&h[min(d, DBINS - 1)], 1);
        }
    }
    __syncthreads();
    if (t < DBINS) { int v = h[t]; if (v) atomicAdd(&hist[t], v); }
}

// exclusive-scan both 64-bin histograms in place (128 threads = 2 waves)
__global__ void k_dscan2(int* __restrict__ hu, int* __restrict__ hi) {
    int t = threadIdx.x;
    int* h = (t < 64) ? hu : hi;
    int tt = t & 63;
    int v = h[tt];
    int s = v;
#pragma unroll
    for (int o = 1; o < 64; o <<= 1) {
        int a = __shfl_up(s, o);
        if (tt >= o) s += a;
    }
    h[tt] = s - v;   // exclusive prefix
}

__global__ __launch_bounds__(256) void k_dscatter(const int* __restrict__ rp,
                                                  int* __restrict__ bpos,
                                                  int* __restrict__ nsort,
                                                  int* __restrict__ nstart,
                                                  int* __restrict__ ndeg, int n) {
    __shared__ int h[DBINS];
    __shared__ int bb[DBINS];
    int t = threadIdx.x;
    if (t < DBINS) h[t] = 0;
    __syncthreads();
    int base = blockIdx.x * 2048;
    int d[8], s0[8];
#pragma unroll
    for (int k = 0; k < 8; k++) {
        int i = base + k * 256 + t;
        if (i < n) {
            int a = rp[i], b = rp[i + 1];
            s0[k] = a;
            d[k] = b - a;
            atomicAdd(&h[min(d[k], DBINS - 1)], 1);
        } else d[k] = -1;
    }
    __syncthreads();
    if (t < DBINS) {
        int v = h[t];
        bb[t] = v ? atomicAdd(&bpos[t], v) : 0;
        h[t] = 0;
    }
    __syncthreads();
#pragma unroll
    for (int k = 0; k < 8; k++) {
        if (d[k] >= 0) {
            int bin = min(d[k], DBINS - 1);
            int p = bb[bin] + atomicAdd(&h[bin], 1);
            nsort[p] = base + k * 256 + t;
            nstart[p] = s0[k];
            ndeg[p] = d[k];
        }
    }
}

// ---------------- fused mean-agg + SAGE transform (degree-sorted tiles) ------
__device__ __forceinline__ void acc_pair(float m, u4v v0, u4v v1,
                                         float* A, float* B) {
#pragma unroll
    for (int k = 0; k < 4; k++) {
        A[2 * k]     = fmaf(m, lo2f(v0[k]), A[2 * k]);
        A[2 * k + 1] = fmaf(m, hi2f(v0[k]), A[2 * k + 1]);
        B[2 * k]     = fmaf(m, lo2f(v1[k]), B[2 * k]);
        B[2 * k + 1] = fmaf(m, hi2f(v1[k]), B[2 * k + 1]);
    }
}

__global__ __launch_bounds__(256) void k_fused(const u16* __restrict__ feat,
                                               const u16* __restrict__ xf,
                                               const u16* __restrict__ wfrag,
                                               const float* __restrict__ bias,
                                               u16* __restrict__ out,
                                               const int* __restrict__ nsort,
                                               const int* __restrict__ nstart,
                                               const int* __restrict__ ndeg,
                                               const int* __restrict__ col,
                                               int ntiles, int relu) {
    __shared__ __align__(16) u16 wsh[8192];   // 16 KB: [which][ks][nb][lane][8]
    int tid = threadIdx.x;
    for (int i = tid; i < 1024; i += 256)
        ((f4v*)wsh)[i] = ((const f4v*)wfrag)[i];
    __syncthreads();

    int lane = tid & 63;
    int q = lane >> 4, c = lane & 15;
    int w = blockIdx.x * 4 + (tid >> 6);
    int stride = gridDim.x * 4;
    float bv[4];
#pragma unroll
    for (int nb = 0; nb < 4; nb++) bv[nb] = bias[nb * 16 + c];

    for (int t = w; t < ntiles; t += stride) {
        int idx = t * 16 + c;
        int node = nsort[idx];      // this lane's node (A-fragment row c)
        int s0 = nstart[idx];       // coalesced row meta (no random rp reads)
        int deg = ndeg[idx];
        float inv = (deg > 0) ? 1.0f / (float)deg : 0.0f;

        // self fragment: issue early, consumed after agg loop
        const s8v* px = (const s8v*)(xf + (size_t)node * DDIM + q * 8);
        s8v x0 = px[0], x1 = px[4];

        float accA[8] = {0.f, 0.f, 0.f, 0.f, 0.f, 0.f, 0.f, 0.f};
        float accB[8] = {0.f, 0.f, 0.f, 0.f, 0.f, 0.f, 0.f, 0.f};

        // 4-edge-unrolled maskless gather; tiles are degree-sorted so the
        // wave-max loop length ~= each lane's own degree (no convoy waste)
        for (int i = 0; __any(i < deg); i += 4) {
            int b = s0 + i;
            int e0 = min(b,     EMAX);
            int e1 = min(b + 1, EMAX);
            int e2 = min(b + 2, EMAX);
            int e3 = min(b + 3, EMAX);
            int r0 = col[e0], r1 = col[e1], r2 = col[e2], r3 = col[e3];
            float m0 = (i     < deg) ? inv : 0.f;
            float m1 = (i + 1 < deg) ? inv : 0.f;
            float m2 = (i + 2 < deg) ? inv : 0.f;
            float m3 = (i + 3 < deg) ? inv : 0.f;
            const u4v* f0 = (const u4v*)(feat + (size_t)r0 * DDIM + q * 8);
            const u4v* f1 = (const u4v*)(feat + (size_t)r1 * DDIM + q * 8);
            const u4v* f2 = (const u4v*)(feat + (size_t)r2 * DDIM + q * 8);
            const u4v* f3 = (const u4v*)(feat + (size_t)r3 * DDIM + q * 8);
            u4v a00 = f0[0], a01 = f0[4];
            u4v a10 = f1[0], a11 = f1[4];
            u4v a20 = f2[0], a21 = f2[4];
            u4v a30 = f3[0], a31 = f3[4];
            acc_pair(m0, a00, a01, accA, accB);
            acc_pair(m1, a10, a11, accA, accB);
            acc_pair(m2, a20, a21, accA, accB);
            acc_pair(m3, a30, a31, accA, accB);
        }

        // mean already folded into masks; convert to A-fragments
        s8v a0, a1;
#pragma unroll
        for (int j = 0; j < 8; j++) {
            a0[j] = (short)f2bf(accA[j]);
            a1[j] = (short)f2bf(accB[j]);
        }

        f4v acc[4];
#pragma unroll
        for (int nb = 0; nb < 4; nb++) {
            acc[nb][0] = bv[nb]; acc[nb][1] = bv[nb];
            acc[nb][2] = bv[nb]; acc[nb][3] = bv[nb];
        }

        // launder LDS offset so weight ds_reads aren't hoisted into VGPRs
        unsigned lz = (unsigned)lane * 8u;
        asm volatile("" : "+v"(lz));
        const u16* wb = wsh + lz;
#pragma unroll
        for (int nb = 0; nb < 4; nb++) {
            s8v wl0 = *(const s8v*)(wb + nb * 512);            // Wl ks=0
            s8v wl1 = *(const s8v*)(wb + 2048 + nb * 512);     // Wl ks=1
            s8v wr0 = *(const s8v*)(wb + 4096 + nb * 512);     // Wr ks=0
            s8v wr1 = *(const s8v*)(wb + 6144 + nb * 512);     // Wr ks=1
            acc[nb] = __builtin_amdgcn_mfma_f32_16x16x32_bf16(a0, wl0, acc[nb], 0, 0, 0);
            acc[nb] = __builtin_amdgcn_mfma_f32_16x16x32_bf16(a1, wl1, acc[nb], 0, 0, 0);
            acc[nb] = __builtin_amdgcn_mfma_f32_16x16x32_bf16(x0, wr0, acc[nb], 0, 0, 0);
            acc[nb] = __builtin_amdgcn_mfma_f32_16x16x32_bf16(x1, wr1, acc[nb], 0, 0, 0);
        }

        // C-fragment rows are permuted node ids: fetch via intra-wave shuffle
        int rn[4];
        rn[0] = __shfl(node, q * 4 + 0);
        rn[1] = __shfl(node, q * 4 + 1);
        rn[2] = __shfl(node, q * 4 + 2);
        rn[3] = __shfl(node, q * 4 + 3);
#pragma unroll
        for (int nb = 0; nb < 4; nb++)
#pragma unroll
            for (int r = 0; r < 4; r++) {
                float v = acc[nb][r];
                if (relu) v = fmaxf(v, 0.f);
                out[(size_t)rn[r] * DDIM + nb * 16 + c] = f2bf(v);
            }
    }
}

// ---------------- final dot predictor (8 edges per wave, 16 B/lane) ----------
__global__ __launch_bounds__(256) void k_dot(const u16* __restrict__ hu,
                                             const u16* __restrict__ hi,
                                             const int* __restrict__ ls,
                                             const int* __restrict__ ld,
                                             float* __restrict__ out) {
    int lane = threadIdx.x & 63;
    int sub = lane >> 3, t8 = lane & 7;
    int w = blockIdx.x * 4 + (threadIdx.x >> 6);
    int stride = gridDim.x * 4;
    const int ngroups = ELl / 8;
    for (int g = w; g < ngroups; g += stride) {
        int e = g * 8 + sub;
        int u = ls[e], it = ld[e];
        s8v av = *(const s8v*)(hu + (size_t)u  * DDIM + t8 * 8);
        s8v bv = *(const s8v*)(hi + (size_t)it * DDIM + t8 * 8);
        float s = 0.f;
#pragma unroll
        for (int k = 0; k < 8; k++) s += bf2f((u16)av[k]) * bf2f((u16)bv[k]);
        s += __shfl_xor(s, 4);
        s += __shfl_xor(s, 2);
        s += __shfl_xor(s, 1);
        if (t8 == 0) out[e] = s;
    }
}

extern "C" void kernel_launch(void* const* d_in, const int* in_sizes, int n_in,
                              void* d_out, int out_size, void* d_ws, size_t ws_size,
                              hipStream_t stream) {
    const float* user_emb = (const float*)d_in[0];
    const float* item_x   = (const float*)d_in[1];
    const float* item_w   = (const float*)d_in[2];
    const float* item_b   = (const float*)d_in[3];
    const float* Wl1_ui = (const float*)d_in[4];
    const float* Wr1_ui = (const float*)d_in[5];
    const float* b1_ui  = (const float*)d_in[6];
    const float* Wl1_iu = (const float*)d_in[7];
    const float* Wr1_iu = (const float*)d_in[8];
    const float* b1_iu  = (const float*)d_in[9];
    const float* Wl2_ui = (const float*)d_in[10];
    const float* Wr2_ui = (const float*)d_in[11];
    const float* b2_ui  = (const float*)d_in[12];
    const float* Wl2_iu = (const float*)d_in[13];
    const float* Wr2_iu = (const float*)d_in[14];
    const float* b2_iu  = (const float*)d_in[15];
    const int* uid  = (const int*)d_in[16];
    const int* esrc = (const int*)d_in[17];
    const int* edst = (const int*)d_in[18];
    const int* lsrc = (const int*)d_in[19];
    const int* ldst = (const int*)d_in[20];
    float* out = (float*)d_out;

    char* ws = (char*)d_ws;
    size_t off = 0;
    auto alloc = [&](size_t bytes) -> void* {
        void* p = ws + off;
        off += (bytes + 255) & ~(size_t)255;
        return p;
    };
    u16* xu_b   = (u16*)alloc((size_t)NUu * DDIM * 2);
    u16* hu1_b  = (u16*)alloc((size_t)NUu * DDIM * 2);
    u16* hu2_b  = (u16*)alloc((size_t)NUu * DDIM * 2);
    u16* xi_b   = (u16*)alloc((size_t)NIi * DDIM * 2);
    u16* hi1_b  = (u16*)alloc((size_t)NIi * DDIM * 2);
    u16* hi2_b  = (u16*)alloc((size_t)NIi * DDIM * 2);
    int* coli = (int*)alloc((size_t)NEe * 4);
    int* colu = (int*)alloc((size_t)NEe * 4);
    int* rpi  = (int*)alloc((size_t)(NIi + 1) * 4);
    int* rpu  = (int*)alloc((size_t)(NUu + 1) * 4);
    int* hist   = (int*)alloc((size_t)NBT * 4);
    int* base_i = (int*)alloc((size_t)(NB_I + 1) * 4);
    int* base_u = (int*)alloc((size_t)(NB_U + 1) * 4);
    int* fr_i   = (int*)alloc((size_t)NB_I * 4);
    int* fr_u   = (int*)alloc((size_t)NB_U * 4);
    u16* wbf    = (u16*)alloc((size_t)40 * 64 * 8 * 2);   // item W, frag order
    u16* wfrag2 = (u16*)alloc((size_t)4 * 8192 * 2);      // 4 transforms x 16 KB
    int* nsort_i  = (int*)alloc((size_t)NIi * 4);
    int* nstart_i = (int*)alloc((size_t)NIi * 4);
    int* ndeg_i   = (int*)alloc((size_t)NIi * 4);
    int* nsort_u  = (int*)alloc((size_t)NUu * 4);
    int* nstart_u = (int*)alloc((size_t)NUu * 4);
    int* ndeg_u   = (int*)alloc((size_t)NUu * 4);
    int* dhist_i  = (int*)alloc((size_t)DBINS * 4);
    int* dhist_u  = (int*)alloc((size_t)DBINS * 4);
    // scatter buffers alias xu_b (16 MB < 64 MB): CSR build runs before k_cast_users
    unsigned* scat_i = (unsigned*)xu_b;
    unsigned* scat_u = (unsigned*)((char*)xu_b + (size_t)NEe * 4);

    // ---- CSR build (bucketed) ----
    hipMemsetAsync(hist, 0, (size_t)NBT * 4, stream);
    hipMemsetAsync(dhist_i, 0, (size_t)DBINS * 4, stream);
    hipMemsetAsync(dhist_u, 0, (size_t)DBINS * 4, stream);
    int nchunks = (NEe + 2047) / 2048;   // 977
    k_hist<<<nchunks, 256, 0, stream>>>(esrc, edst, hist);
    k_bucket_scan<<<1, 256, 0, stream>>>(hist, base_i, fr_i, base_u, fr_u, rpi, rpu);
    k_scatter<<<nchunks, 256, 0, stream>>>(esrc, edst, fr_i, fr_u, scat_i, scat_u);
    k_bfill<<<NB_I, 256, 0, stream>>>(scat_i, base_i, rpi, coli, SH_I, BSZL_I, NIi);
    k_bfill<<<NB_U, 256, 0, stream>>>(scat_u, base_u, rpu, colu, SH_U, BSZL_U, NUu);

    // ---- degree sort (counting sort, 64 bins) ----
    int nci = (NIi + 2047) / 2048;   // 49
    int ncu = (NUu + 2047) / 2048;   // 245
    k_dhist<<<nci, 256, 0, stream>>>(rpi, dhist_i, NIi);
    k_dhist<<<ncu, 256, 0, stream>>>(rpu, dhist_u, NUu);
    k_dscan2<<<1, 128, 0, stream>>>(dhist_u, dhist_i);
    k_dscatter<<<nci, 256, 0, stream>>>(rpi, dhist_i, nsort_i, nstart_i, ndeg_i, NIi);
    k_dscatter<<<ncu, 256, 0, stream>>>(rpu, dhist_u, nsort_u, nstart_u, ndeg_u, NUu);

    // ---- input features (after CSR build: scat_* alias xu_b) ----
    k_cast_w<<<10, 256, 0, stream>>>(item_w, wbf);
    k_cast_w8<<<16, 256, 0, stream>>>(Wl1_ui, Wr1_ui, Wl1_iu, Wr1_iu,
                                      Wl2_ui, Wr2_ui, Wl2_iu, Wr2_iu, wfrag2);
    k_cast_users<<<NUu * 16 / 256, 256, 0, stream>>>(user_emb, uid, xu_b);
    k_item_lin2<<<1024, 256, 0, stream>>>(item_x, wbf, item_b, xi_b);

    const int NT_I = NIi / 16;   // 6250
    const int NT_U = NUu / 16;   // 31250

    // layer 1 (fused agg + transform, degree-sorted tiles)
    k_fused<<<1568, 256, 0, stream>>>(xu_b, xi_b, wfrag2 + 0 * 8192, b1_ui,
                                      hi1_b, nsort_i, nstart_i, ndeg_i, coli, NT_I, 1);
    k_fused<<<2048, 256, 0, stream>>>(xi_b, xu_b, wfrag2 + 1 * 8192, b1_iu,
                                      hu1_b, nsort_u, nstart_u, ndeg_u, colu, NT_U, 1);
    // layer 2
    k_fused<<<1568, 256, 0, stream>>>(hu1_b, hi1_b, wfrag2 + 2 * 8192, b2_ui,
                                      hi2_b, nsort_i, nstart_i, ndeg_i, coli, NT_I, 0);
    k_fused<<<2048, 256, 0, stream>>>(hi1_b, hu1_b, wfrag2 + 3 * 8192, b2_iu,
                                      hu2_b, nsort_u, nstart_u, ndeg_u, colu, NT_U, 0);

    // predictor
    k_dot<<<2048, 256, 0, stream>>>(hu2_b, hi2_b, lsrc, ldst, out);
}

// Round 4
// 773.186 us; speedup vs baseline: 1.1729x; 1.0521x over previous
//
#include <hip/hip_runtime.h>

#define NUu 500000
#define NIi 100000
#define FDIM 300
#define DDIM 64
#define NEe 2000000
#define ELl 1000000
#define EMAX (NEe - 1)

// bucket config for CSR build
#define BSZL_I 9      // 512 items per bucket
#define BSZL_U 10     // 1024 users per bucket
#define NB_I 196      // ceil(NIi/512)
#define NB_U 489      // ceil(NUu/1024)
#define NBT (NB_I + NB_U)   // 685
#define SH_I 19       // src < 2^19 packed low, d_local(9b)<<19
#define SH_U 17       // dst < 2^17 packed low, s_local(10b)<<17
#define EPB 8192      // edges per hist/scatter block
#define KPB 32        // EPB/256

#define DBINS 64      // degree-sort bins (clamped)

typedef __attribute__((ext_vector_type(8))) short s8v;
typedef __attribute__((ext_vector_type(4))) short s4v;
typedef __attribute__((ext_vector_type(4))) float f4v;
typedef __attribute__((ext_vector_type(4))) unsigned u4v;
typedef unsigned short u16;

__device__ __forceinline__ float bf2f(u16 h) {
    union { unsigned u; float f; } x; x.u = ((unsigned)h) << 16; return x.f;
}
__device__ __forceinline__ u16 f2bf(float f) {
    union { float f; unsigned u; } x; x.f = f;
    unsigned u = x.u;
    u += 0x7FFFu + ((u >> 16) & 1u);   // round-to-nearest-even
    return (u16)(u >> 16);
}
__device__ __forceinline__ float lo2f(unsigned u) {
    union { unsigned x; float f; } c; c.x = u << 16; return c.f;
}
__device__ __forceinline__ float hi2f(unsigned u) {
    union { unsigned x; float f; } c; c.x = u & 0xffff0000u; return c.f;
}

// ---------------- cast user embeddings (with user_node_id gather) to bf16 ----
__global__ __launch_bounds__(256) void k_cast_users(const float* __restrict__ ue,
                                                    const int* __restrict__ uid,
                                                    u16* __restrict__ xu) {
    int idx = blockIdx.x * 256 + threadIdx.x;   // one thread = 4 elems
    int n  = idx >> 4;
    int d0 = (idx & 15) * 4;
    int src = uid[n];
    const float4* p = (const float4*)(ue + (size_t)src * DDIM + d0);
    float4 v = *p;
    s4v o;
    o[0] = (short)f2bf(v.x); o[1] = (short)f2bf(v.y);
    o[2] = (short)f2bf(v.z); o[3] = (short)f2bf(v.w);
    *(s4v*)(xu + (size_t)n * DDIM + d0) = o;
}

// ---------------- cast item_lin_w to bf16 in MFMA B-fragment order ----------
__global__ __launch_bounds__(256) void k_cast_w(const float* __restrict__ W,
                                                u16* __restrict__ wbf) {
    int idx = blockIdx.x * 256 + threadIdx.x;   // 2560 lane-slots
    if (idx >= 2560) return;
    int f = idx >> 6, lane = idx & 63;
    int q = lane >> 4, c = lane & 15;
    int kstep = f >> 2, nb = f & 3;
    u16* dst = wbf + (size_t)idx * 8;
#pragma unroll
    for (int j = 0; j < 8; j++) {
        int k = kstep * 32 + q * 8 + j;
        float v = (k < FDIM) ? W[k * DDIM + nb * 16 + c] : 0.f;
        dst[j] = f2bf(v);
    }
}

// ---------------- cast the 8 SAGE weight matrices to B-fragment order --------
__global__ __launch_bounds__(256) void k_cast_w8(
    const float* __restrict__ W0, const float* __restrict__ W1,
    const float* __restrict__ W2, const float* __restrict__ W3,
    const float* __restrict__ W4, const float* __restrict__ W5,
    const float* __restrict__ W6, const float* __restrict__ W7,
    u16* __restrict__ out) {
    int idx = blockIdx.x * 256 + threadIdx.x;   // 4096 slots
    if (idx >= 4096) return;
    int wm = idx >> 9;
    int s = idx & 511;
    int ks = s >> 8, nb = (s >> 6) & 3, lane = s & 63;
    int q = lane >> 4, c = lane & 15;
    const float* W;
    switch (wm) {
        case 0: W = W0; break; case 1: W = W1; break;
        case 2: W = W2; break; case 3: W = W3; break;
        case 4: W = W4; break; case 5: W = W5; break;
        case 6: W = W6; break; default: W = W7; break;
    }
    u16* dst = out + (size_t)idx * 8;
#pragma unroll
    for (int j = 0; j < 8; j++) {
        int row = ks * 32 + q * 8 + j;
        dst[j] = f2bf(W[row * DDIM + nb * 16 + c]);
    }
}

// ---------------- item linear via MFMA: xi = item_x @ W + b ------------------
__global__ __launch_bounds__(256) void k_item_lin2(const float* __restrict__ ix,
                                                   const u16* __restrict__ wbf,
                                                   const float* __restrict__ b,
                                                   u16* __restrict__ xi) {
    __shared__ __align__(16) u16 wl[40 * 64 * 8];   // 40960 B
    int tid = threadIdx.x;
    for (int i = tid; i < 2560; i += 256)
        ((f4v*)wl)[i] = ((const f4v*)wbf)[i];
    __syncthreads();

    int lane = tid & 63;
    int q = lane >> 4, c = lane & 15;
    float bv[4];
#pragma unroll
    for (int nb = 0; nb < 4; nb++) bv[nb] = b[nb * 16 + c];

    int w = blockIdx.x * 4 + (tid >> 6);
    int stride = gridDim.x * 4;
    const int NT = NIi / 16;   // 6250
    for (int t = w; t < NT; t += stride) {
        int row = t * 16 + c;
        const float* xr = ix + (size_t)row * FDIM;
        f4v acc[4];
#pragma unroll
        for (int nb = 0; nb < 4; nb++) {
            acc[nb][0] = bv[nb]; acc[nb][1] = bv[nb];
            acc[nb][2] = bv[nb]; acc[nb][3] = bv[nb];
        }
#pragma unroll
        for (int ks = 0; ks < 10; ks++) {
            s8v a;
            if (ks < 9 || q == 0) {
                float4 v0 = *(const float4*)(xr + ks * 32 + q * 8);
                float4 v1 = *(const float4*)(xr + ks * 32 + q * 8 + 4);
                a[0] = (short)f2bf(v0.x); a[1] = (short)f2bf(v0.y);
                a[2] = (short)f2bf(v0.z); a[3] = (short)f2bf(v0.w);
                a[4] = (short)f2bf(v1.x); a[5] = (short)f2bf(v1.y);
                a[6] = (short)f2bf(v1.z); a[7] = (short)f2bf(v1.w);
            } else {   // ks==9, q==1: k = 296..303, valid only 296..299
                float4 v0 = *(const float4*)(xr + 296);
                a[0] = (short)f2bf(v0.x); a[1] = (short)f2bf(v0.y);
                a[2] = (short)f2bf(v0.z); a[3] = (short)f2bf(v0.w);
                a[4] = 0; a[5] = 0; a[6] = 0; a[7] = 0;
            }
#pragma unroll
            for (int nb = 0; nb < 4; nb++) {
                s8v bb = *(const s8v*)(wl + ((size_t)(ks * 4 + nb) * 64 + lane) * 8);
                acc[nb] = __builtin_amdgcn_mfma_f32_16x16x32_bf16(a, bb, acc[nb], 0, 0, 0);
            }
        }
#pragma unroll
        for (int nb = 0; nb < 4; nb++)
#pragma unroll
            for (int r = 0; r < 4; r++)
                xi[(size_t)(t * 16 + q * 4 + r) * DDIM + nb * 16 + c] = f2bf(acc[nb][r]);
    }
}

// ---------------- CSR build: bucketed multisplit ------------------------------
__global__ __launch_bounds__(256) void k_hist(const int* __restrict__ src,
                                              const int* __restrict__ dst,
                                              int* __restrict__ hist) {
    __shared__ int h[NBT];
    int t = threadIdx.x;
    for (int c = t; c < NBT; c += 256) h[c] = 0;
    __syncthreads();
    int base = blockIdx.x * EPB;
    for (int k = 0; k < KPB; k++) {
        int e = base + k * 256 + t;
        if (e < NEe) {
            int s = src[e], d = dst[e];
            atomicAdd(&h[d >> BSZL_I], 1);
            atomicAdd(&h[NB_I + (s >> BSZL_U)], 1);
        }
    }
    __syncthreads();
    for (int c = t; c < NBT; c += 256) {
        int n = h[c];
        if (n) atomicAdd(&hist[c], n);
    }
}

__device__ __forceinline__ void scanN(const int* __restrict__ cnt, int n, int total,
                                      int* __restrict__ base, int* __restrict__ frontier,
                                      int* sb) {
    int t = threadIdx.x;
    int v[8]; int s = 0;
#pragma unroll
    for (int i = 0; i < 8; i++) {
        int idx = t * 8 + i;
        v[i] = (idx < n) ? cnt[idx] : 0;
        s += v[i];
    }
    sb[t] = s; __syncthreads();
    for (int o = 1; o < 256; o <<= 1) {
        int a = (t >= o) ? sb[t - o] : 0;
        __syncthreads();
        sb[t] += a;
        __syncthreads();
    }
    int run = sb[t] - s;
#pragma unroll
    for (int i = 0; i < 8; i++) {
        int idx = t * 8 + i;
        if (idx < n) { base[idx] = run; frontier[idx] = run; }
        run += v[i];
    }
    if (t == 0) base[n] = total;
    __syncthreads();
}

__global__ __launch_bounds__(256) void k_bucket_scan(const int* __restrict__ hist,
                                                     int* __restrict__ base_i, int* __restrict__ fr_i,
                                                     int* __restrict__ base_u, int* __restrict__ fr_u,
                                                     int* __restrict__ rpi, int* __restrict__ rpu) {
    __shared__ int sb[256];
    scanN(hist, NB_I, NEe, base_i, fr_i, sb);
    scanN(hist + NB_I, NB_U, NEe, base_u, fr_u, sb);
    if (threadIdx.x == 0) { rpi[NIi] = NEe; rpu[NUu] = NEe; }
}

__global__ __launch_bounds__(256) void k_scatter(const int* __restrict__ src,
                                                 const int* __restrict__ dst,
                                                 int* __restrict__ fr_i, int* __restrict__ fr_u,
                                                 unsigned* __restrict__ scat_i,
                                                 unsigned* __restrict__ scat_u) {
    __shared__ int h[NBT];
    int t = threadIdx.x;
    for (int c = t; c < NBT; c += 256) h[c] = 0;
    __syncthreads();
    int base = blockIdx.x * EPB;
    for (int k = 0; k < KPB; k++) {
        int e = base + k * 256 + t;
        if (e < NEe) {
            int s = src[e], d = dst[e];
            atomicAdd(&h[d >> BSZL_I], 1);
            atomicAdd(&h[NB_I + (s >> BSZL_U)], 1);
        }
    }
    __syncthreads();
    for (int c = t; c < NBT; c += 256) {
        int n = h[c];
        if (n) {
            int b = (c < NB_I) ? atomicAdd(&fr_i[c], n) : atomicAdd(&fr_u[c - NB_I], n);
            h[c] = b;
        }
    }
    __syncthreads();
    for (int k = 0; k < KPB; k++) {
        int e = base + k * 256 + t;
        if (e < NEe) {
            int s = src[e], d = dst[e];
            int p = atomicAdd(&h[d >> BSZL_I], 1);
            scat_i[p] = (unsigned)s | ((unsigned)(d & ((1 << BSZL_I) - 1)) << SH_I);
            int q = atomicAdd(&h[NB_I + (s >> BSZL_U)], 1);
            scat_u[q] = (unsigned)d | ((unsigned)(s & ((1 << BSZL_U) - 1)) << SH_U);
        }
    }
}

__global__ __launch_bounds__(256) void k_bfill(const unsigned* __restrict__ scat,
                                               const int* __restrict__ base,
                                               int* __restrict__ rp, int* __restrict__ col,
                                               int shift, int bszlog, int ntotal) {
    __shared__ int cnt[1024];
    __shared__ int pos[1024];
    __shared__ int sb[256];
    int b = blockIdx.x;
    int t = threadIdx.x;
    int e0 = base[b], e1 = base[b + 1];
    int node0 = b << bszlog;
    int bsz = 1 << bszlog;
    unsigned mask = (1u << shift) - 1u;

    for (int c = t; c < bsz; c += 256) cnt[c] = 0;
    __syncthreads();
    for (int e = e0 + t; e < e1; e += 256) {
        unsigned v = scat[e];
        atomicAdd(&cnt[v >> shift], 1);
    }
    __syncthreads();
    int per = bsz >> 8;   // 2 (item, bsz=512) or 4 (user, bsz=1024)
    int loc[4]; int ls = 0;
#pragma unroll
    for (int i = 0; i < 4; i++) {
        loc[i] = (i < per) ? cnt[t * per + i] : 0;
        ls += loc[i];
    }
    sb[t] = ls; __syncthreads();
    for (int o = 1; o < 256; o <<= 1) {
        int a = (t >= o) ? sb[t - o] : 0;
        __syncthreads();
        sb[t] += a;
        __syncthreads();
    }
    int run = e0 + sb[t] - ls;
#pragma unroll
    for (int i = 0; i < 4; i++) {
        if (i < per) {
            int idx = t * per + i;
            int node = node0 + idx;
            if (node < ntotal) rp[node] = run;
            pos[idx] = run;
            run += loc[i];
        }
    }
    __syncthreads();
    for (int e = e0 + t; e < e1; e += 256) {
        unsigned v = scat[e];
        int l = v >> shift;
        int p = atomicAdd(&pos[l], 1);
        col[p] = (int)(v & mask);
    }
}

// ---------------- degree counting-sort (64 bins) -----------------------------
__global__ __launch_bounds__(256) void k_dhist(const int* __restrict__ rp,
                                               int* __restrict__ hist, int n) {
    __shared__ int h[DBINS];
    int t = threadIdx.x;
    if (t < DBINS) h[t] = 0;
    __syncthreads();
    int base = blockIdx.x * 2048;
#pragma unroll
    for (int k = 0; k < 8; k++) {
        int i = base + k * 256 + t;
        if (i < n) {
            int d = rp[i + 1] - rp[i];
            atomicAdd(&h[min(d, DBINS - 1)], 1);
        }
    }
    __syncthreads();
    if (t < DBINS) { int v = h[t]; if (v) atomicAdd(&hist[t], v); }
}

// exclusive-scan both 64-bin histograms in place (128 threads = 2 waves)
__global__ void k_dscan2(int* __restrict__ hu, int* __restrict__ hi) {
    int t = threadIdx.x;
    int* h = (t < 64) ? hu : hi;
    int tt = t & 63;
    int v = h[tt];
    int s = v;
#pragma unroll
    for (int o = 1; o < 64; o <<= 1) {
        int a = __shfl_up(s, o);
        if (tt >= o) s += a;
    }
    h[tt] = s - v;   // exclusive prefix
}

__global__ __launch_bounds__(256) void k_dscatter(const int* __restrict__ rp,
                                                  int* __restrict__ bpos,
                                                  int* __restrict__ nsort,
                                                  int2* __restrict__ nmeta, int n) {
    __shared__ int h[DBINS];
    __shared__ int bb[DBINS];
    int t = threadIdx.x;
    if (t < DBINS) h[t] = 0;
    __syncthreads();
    int base = blockIdx.x * 2048;
    int d[8], s0[8];
#pragma unroll
    for (int k = 0; k < 8; k++) {
        int i = base + k * 256 + t;
        if (i < n) {
            int a = rp[i], b = rp[i + 1];
            s0[k] = a;
            d[k] = b - a;
            atomicAdd(&h[min(d[k], DBINS - 1)], 1);
        } else d[k] = -1;
    }
    __syncthreads();
    if (t < DBINS) {
        int v = h[t];
        bb[t] = v ? atomicAdd(&bpos[t], v) : 0;
        h[t] = 0;
    }
    __syncthreads();
#pragma unroll
    for (int k = 0; k < 8; k++) {
        if (d[k] >= 0) {
            int bin = min(d[k], DBINS - 1);
            int p = bb[bin] + atomicAdd(&h[bin], 1);
            nsort[p] = base + k * 256 + t;
            nmeta[p] = make_int2(s0[k], d[k]);
        }
    }
}

// ---------------- fused mean-agg + SAGE transform (degree-sorted tiles) ------
__device__ __forceinline__ void acc_pair(float m, u4v v0, u4v v1,
                                         float* A, float* B) {
#pragma unroll
    for (int k = 0; k < 4; k++) {
        A[2 * k]     = fmaf(m, lo2f(v0[k]), A[2 * k]);
        A[2 * k + 1] = fmaf(m, hi2f(v0[k]), A[2 * k + 1]);
        B[2 * k]     = fmaf(m, lo2f(v1[k]), B[2 * k]);
        B[2 * k + 1] = fmaf(m, hi2f(v1[k]), B[2 * k + 1]);
    }
}

__global__ __launch_bounds__(256) void k_fused(const u16* __restrict__ feat,
                                               const u16* __restrict__ xf,
                                               const u16* __restrict__ wfrag,
                                               const float* __restrict__ bias,
                                               u16* __restrict__ out,
                                               const int* __restrict__ nsort,
                                               const int2* __restrict__ nmeta,
                                               const int* __restrict__ col,
                                               int ntiles, int relu) {
    __shared__ __align__(16) u16 wsh[8192];   // 16 KB: [which][ks][nb][lane][8]
    int tid = threadIdx.x;
    for (int i = tid; i < 1024; i += 256)
        ((f4v*)wsh)[i] = ((const f4v*)wfrag)[i];
    __syncthreads();

    int lane = tid & 63;
    int q = lane >> 4, c = lane & 15;
    int w = blockIdx.x * 4 + (tid >> 6);
    int stride = gridDim.x * 4;
    float bv[4];
#pragma unroll
    for (int nb = 0; nb < 4; nb++) bv[nb] = bias[nb * 16 + c];

    for (int t = w; t < ntiles; t += stride) {
        int idx = t * 16 + c;
        int node = nsort[idx];      // this lane's node (A-fragment row c)
        int2 meta = nmeta[idx];     // {row start, degree} (coalesced 8B)
        int s0 = meta.x;
        int deg = meta.y;
        float inv = (deg > 0) ? 1.0f / (float)deg : 0.0f;

        // self fragment: issue early, consumed after agg loop
        const s8v* px = (const s8v*)(xf + (size_t)node * DDIM + q * 8);
        s8v x0 = px[0], x1 = px[4];

        float accA[8] = {0.f, 0.f, 0.f, 0.f, 0.f, 0.f, 0.f, 0.f};
        float accB[8] = {0.f, 0.f, 0.f, 0.f, 0.f, 0.f, 0.f, 0.f};

        // 4-edge-unrolled maskless gather; tiles are degree-sorted so the
        // wave-max loop length ~= each lane's own degree (no convoy waste)
        for (int i = 0; __any(i < deg); i += 4) {
            int b = s0 + i;
            int e0 = min(b,     EMAX);
            int e1 = min(b + 1, EMAX);
            int e2 = min(b + 2, EMAX);
            int e3 = min(b + 3, EMAX);
            int r0 = col[e0], r1 = col[e1], r2 = col[e2], r3 = col[e3];
            float m0 = (i     < deg) ? inv : 0.f;
            float m1 = (i + 1 < deg) ? inv : 0.f;
            float m2 = (i + 2 < deg) ? inv : 0.f;
            float m3 = (i + 3 < deg) ? inv : 0.f;
            const u4v* f0 = (const u4v*)(feat + (size_t)r0 * DDIM + q * 8);
            const u4v* f1 = (const u4v*)(feat + (size_t)r1 * DDIM + q * 8);
            const u4v* f2 = (const u4v*)(feat + (size_t)r2 * DDIM + q * 8);
            const u4v* f3 = (const u4v*)(feat + (size_t)r3 * DDIM + q * 8);
            u4v a00 = f0[0], a01 = f0[4];
            u4v a10 = f1[0], a11 = f1[4];
            u4v a20 = f2[0], a21 = f2[4];
            u4v a30 = f3[0], a31 = f3[4];
            acc_pair(m0, a00, a01, accA, accB);
            acc_pair(m1, a10, a11, accA, accB);
            acc_pair(m2, a20, a21, accA, accB);
            acc_pair(m3, a30, a31, accA, accB);
        }

        // mean already folded into masks; convert to A-fragments
        s8v a0, a1;
#pragma unroll
        for (int j = 0; j < 8; j++) {
            a0[j] = (short)f2bf(accA[j]);
            a1[j] = (short)f2bf(accB[j]);
        }

        f4v acc[4];
#pragma unroll
        for (int nb = 0; nb < 4; nb++) {
            acc[nb][0] = bv[nb]; acc[nb][1] = bv[nb];
            acc[nb][2] = bv[nb]; acc[nb][3] = bv[nb];
        }

        // launder LDS offset so weight ds_reads aren't hoisted into VGPRs
        unsigned lz = (unsigned)lane * 8u;
        asm volatile("" : "+v"(lz));
        const u16* wb = wsh + lz;
#pragma unroll
        for (int nb = 0; nb < 4; nb++) {
            s8v wl0 = *(const s8v*)(wb + nb * 512);            // Wl ks=0
            s8v wl1 = *(const s8v*)(wb + 2048 + nb * 512);     // Wl ks=1
            s8v wr0 = *(const s8v*)(wb + 4096 + nb * 512);     // Wr ks=0
            s8v wr1 = *(const s8v*)(wb + 6144 + nb * 512);     // Wr ks=1
            acc[nb] = __builtin_amdgcn_mfma_f32_16x16x32_bf16(a0, wl0, acc[nb], 0, 0, 0);
            acc[nb] = __builtin_amdgcn_mfma_f32_16x16x32_bf16(a1, wl1, acc[nb], 0, 0, 0);
            acc[nb] = __builtin_amdgcn_mfma_f32_16x16x32_bf16(x0, wr0, acc[nb], 0, 0, 0);
            acc[nb] = __builtin_amdgcn_mfma_f32_16x16x32_bf16(x1, wr1, acc[nb], 0, 0, 0);
        }

        // C-fragment rows are permuted node ids: fetch via intra-wave shuffle
        int rn[4];
        rn[0] = __shfl(node, q * 4 + 0);
        rn[1] = __shfl(node, q * 4 + 1);
        rn[2] = __shfl(node, q * 4 + 2);
        rn[3] = __shfl(node, q * 4 + 3);
#pragma unroll
        for (int nb = 0; nb < 4; nb++)
#pragma unroll
            for (int r = 0; r < 4; r++) {
                float v = acc[nb][r];
                if (relu) v = fmaxf(v, 0.f);
                out[(size_t)rn[r] * DDIM + nb * 16 + c] = f2bf(v);
            }
    }
}

// ---------------- final dot predictor (8 edges per wave, 16 B/lane) ----------
__global__ __launch_bounds__(256) void k_dot(const u16* __restrict__ hu,
                                             const u16* __restrict__ hi,
                                             const int* __restrict__ ls,
                                             const int* __restrict__ ld,
                                             float* __restrict__ out) {
    int lane = threadIdx.x & 63;
    int sub = lane >> 3, t8 = lane & 7;
    int w = blockIdx.x * 4 + (threadIdx.x >> 6);
    int stride = gridDim.x * 4;
    const int ngroups = ELl / 8;
    for (int g = w; g < ngroups; g += stride) {
        int e = g * 8 + sub;
        int u = ls[e], it = ld[e];
        s8v av = *(const s8v*)(hu + (size_t)u  * DDIM + t8 * 8);
        s8v bv = *(const s8v*)(hi + (size_t)it * DDIM + t8 * 8);
        float s = 0.f;
#pragma unroll
        for (int k = 0; k < 8; k++) s += bf2f((u16)av[k]) * bf2f((u16)bv[k]);
        s += __shfl_xor(s, 4);
        s += __shfl_xor(s, 2);
        s += __shfl_xor(s, 1);
        if (t8 == 0) out[e] = s;
    }
}

extern "C" void kernel_launch(void* const* d_in, const int* in_sizes, int n_in,
                              void* d_out, int out_size, void* d_ws, size_t ws_size,
                              hipStream_t stream) {
    const float* user_emb = (const float*)d_in[0];
    const float* item_x   = (const float*)d_in[1];
    const float* item_w   = (const float*)d_in[2];
    const float* item_b   = (const float*)d_in[3];
    const float* Wl1_ui = (const float*)d_in[4];
    const float* Wr1_ui = (const float*)d_in[5];
    const float* b1_ui  = (const float*)d_in[6];
    const float* Wl1_iu = (const float*)d_in[7];
    const float* Wr1_iu = (const float*)d_in[8];
    const float* b1_iu  = (const float*)d_in[9];
    const float* Wl2_ui = (const float*)d_in[10];
    const float* Wr2_ui = (const float*)d_in[11];
    const float* b2_ui  = (const float*)d_in[12];
    const float* Wl2_iu = (const float*)d_in[13];
    const float* Wr2_iu = (const float*)d_in[14];
    const float* b2_iu  = (const float*)d_in[15];
    const int* uid  = (const int*)d_in[16];
    const int* esrc = (const int*)d_in[17];
    const int* edst = (const int*)d_in[18];
    const int* lsrc = (const int*)d_in[19];
    const int* ldst = (const int*)d_in[20];
    float* out = (float*)d_out;

    char* ws = (char*)d_ws;
    size_t off = 0;
    auto alloc = [&](size_t bytes) -> void* {
        void* p = ws + off;
        off += (bytes + 255) & ~(size_t)255;
        return p;
    };
    u16* xu_b   = (u16*)alloc((size_t)NUu * DDIM * 2);
    u16* hu1_b  = (u16*)alloc((size_t)NUu * DDIM * 2);
    u16* hu2_b  = (u16*)alloc((size_t)NUu * DDIM * 2);
    u16* xi_b   = (u16*)alloc((size_t)NIi * DDIM * 2);
    u16* hi1_b  = (u16*)alloc((size_t)NIi * DDIM * 2);
    u16* hi2_b  = (u16*)alloc((size_t)NIi * DDIM * 2);
    int* coli = (int*)alloc((size_t)NEe * 4);
    int* colu = (int*)alloc((size_t)NEe * 4);
    int* rpi  = (int*)alloc((size_t)(NIi + 1) * 4);
    int* rpu  = (int*)alloc((size_t)(NUu + 1) * 4);
    int* hist   = (int*)alloc((size_t)NBT * 4);
    int* base_i = (int*)alloc((size_t)(NB_I + 1) * 4);
    int* base_u = (int*)alloc((size_t)(NB_U + 1) * 4);
    int* fr_i   = (int*)alloc((size_t)NB_I * 4);
    int* fr_u   = (int*)alloc((size_t)NB_U * 4);
    u16* wbf    = (u16*)alloc((size_t)40 * 64 * 8 * 2);   // item W, frag order
    u16* wfrag2 = (u16*)alloc((size_t)4 * 8192 * 2);      // 4 transforms x 16 KB
    int* nsort_i  = (int*)alloc((size_t)NIi * 4);
    int2* nmeta_i = (int2*)alloc((size_t)NIi * 8);
    int* nsort_u  = (int*)alloc((size_t)NUu * 4);
    int2* nmeta_u = (int2*)alloc((size_t)NUu * 8);
    int* dhist_i  = (int*)alloc((size_t)DBINS * 4);
    int* dhist_u  = (int*)alloc((size_t)DBINS * 4);
    // scatter buffers alias xu_b (16 MB < 64 MB): CSR build runs before k_cast_users
    unsigned* scat_i = (unsigned*)xu_b;
    unsigned* scat_u = (unsigned*)((char*)xu_b + (size_t)NEe * 4);

    // ---- CSR build (bucketed) ----
    hipMemsetAsync(hist, 0, (size_t)NBT * 4, stream);
    hipMemsetAsync(dhist_i, 0, (size_t)DBINS * 4, stream);
    hipMemsetAsync(dhist_u, 0, (size_t)DBINS * 4, stream);
    int nchunks = (NEe + EPB - 1) / EPB;   // 245
    k_hist<<<nchunks, 256, 0, stream>>>(esrc, edst, hist);
    k_bucket_scan<<<1, 256, 0, stream>>>(hist, base_i, fr_i, base_u, fr_u, rpi, rpu);
    k_scatter<<<nchunks, 256, 0, stream>>>(esrc, edst, fr_i, fr_u, scat_i, scat_u);
    k_bfill<<<NB_I, 256, 0, stream>>>(scat_i, base_i, rpi, coli, SH_I, BSZL_I, NIi);
    k_bfill<<<NB_U, 256, 0, stream>>>(scat_u, base_u, rpu, colu, SH_U, BSZL_U, NUu);

    // ---- degree sort (counting sort, 64 bins) ----
    int nci = (NIi + 2047) / 2048;   // 49
    int ncu = (NUu + 2047) / 2048;   // 245
    k_dhist<<<nci, 256, 0, stream>>>(rpi, dhist_i, NIi);
    k_dhist<<<ncu, 256, 0, stream>>>(rpu, dhist_u, NUu);
    k_dscan2<<<1, 128, 0, stream>>>(dhist_u, dhist_i);
    k_dscatter<<<nci, 256, 0, stream>>>(rpi, dhist_i, nsort_i, nmeta_i, NIi);
    k_dscatter<<<ncu, 256, 0, stream>>>(rpu, dhist_u, nsort_u, nmeta_u, NUu);

    // ---- input features (after CSR build: scat_* alias xu_b) ----
    k_cast_w<<<10, 256, 0, stream>>>(item_w, wbf);
    k_cast_w8<<<16, 256, 0, stream>>>(Wl1_ui, Wr1_ui, Wl1_iu, Wr1_iu,
                                      Wl2_ui, Wr2_ui, Wl2_iu, Wr2_iu, wfrag2);
    k_cast_users<<<NUu * 16 / 256, 256, 0, stream>>>(user_emb, uid, xu_b);
    k_item_lin2<<<1024, 256, 0, stream>>>(item_x, wbf, item_b, xi_b);

    const int NT_I = NIi / 16;   // 6250
    const int NT_U = NUu / 16;   // 31250

    // layer 1 (fused agg + transform, degree-sorted tiles)
    k_fused<<<1568, 256, 0, stream>>>(xu_b, xi_b, wfrag2 + 0 * 8192, b1_ui,
                                      hi1_b, nsort_i, nmeta_i, coli, NT_I, 1);
    k_fused<<<2048, 256, 0, stream>>>(xi_b, xu_b, wfrag2 + 1 * 8192, b1_iu,
                                      hu1_b, nsort_u, nmeta_u, colu, NT_U, 1);
    // layer 2
    k_fused<<<1568, 256, 0, stream>>>(hu1_b, hi1_b, wfrag2 + 2 * 8192, b2_ui,
                                      hi2_b, nsort_i, nmeta_i, coli, NT_I, 0);
    k_fused<<<2048, 256, 0, stream>>>(hi1_b, hu1_b, wfrag2 + 3 * 8192, b2_iu,
                                      hu2_b, nsort_u, nmeta_u, colu, NT_U, 0);

    // predictor
    k_dot<<<2048, 256, 0, stream>>>(hu2_b, hi2_b, lsrc, ldst, out);
}

// Round 6
// 771.549 us; speedup vs baseline: 1.1754x; 1.0021x over previous
//
#include <hip/hip_runtime.h>

#define NUu 500000
#define NIi 100000
#define FDIM 300
#define DDIM 64
#define NEe 2000000
#define ELl 1000000
#define EMAX (NEe - 1)

// bucket config for CSR build
#define BSZL_I 9      // 512 items per bucket
#define BSZL_U 10     // 1024 users per bucket
#define NB_I 196      // ceil(NIi/512)
#define NB_U 489      // ceil(NUu/1024)
#define NBT (NB_I + NB_U)   // 685
#define SH_I 19       // src < 2^19 packed low, d_local(9b)<<19
#define SH_U 17       // dst < 2^17 packed low, s_local(10b)<<17
#define EPB 8192      // edges per hist/scatter block
#define KPB 32        // EPB/256

#define DBINS 64      // degree-sort bins (clamped)

typedef __attribute__((ext_vector_type(8))) short s8v;
typedef __attribute__((ext_vector_type(4))) short s4v;
typedef __attribute__((ext_vector_type(4))) float f4v;
typedef __attribute__((ext_vector_type(4))) unsigned u4v;
typedef unsigned short u16;

__device__ __forceinline__ float bf2f(u16 h) {
    union { unsigned u; float f; } x; x.u = ((unsigned)h) << 16; return x.f;
}
__device__ __forceinline__ u16 f2bf(float f) {
    union { float f; unsigned u; } x; x.f = f;
    unsigned u = x.u;
    u += 0x7FFFu + ((u >> 16) & 1u);   // round-to-nearest-even
    return (u16)(u >> 16);
}
__device__ __forceinline__ float lo2f(unsigned u) {
    union { unsigned x; float f; } c; c.x = u << 16; return c.f;
}
__device__ __forceinline__ float hi2f(unsigned u) {
    union { unsigned x; float f; } c; c.x = u & 0xffff0000u; return c.f;
}

// ---------------- cast user embeddings (with user_node_id gather) to bf16 ----
__global__ __launch_bounds__(256) void k_cast_users(const float* __restrict__ ue,
                                                    const int* __restrict__ uid,
                                                    u16* __restrict__ xu) {
    int idx = blockIdx.x * 256 + threadIdx.x;   // one thread = 4 elems
    int n  = idx >> 4;
    int d0 = (idx & 15) * 4;
    int src = uid[n];
    const float4* p = (const float4*)(ue + (size_t)src * DDIM + d0);
    float4 v = *p;
    s4v o;
    o[0] = (short)f2bf(v.x); o[1] = (short)f2bf(v.y);
    o[2] = (short)f2bf(v.z); o[3] = (short)f2bf(v.w);
    *(s4v*)(xu + (size_t)n * DDIM + d0) = o;
}

// ---------------- cast item_lin_w to bf16 in MFMA B-fragment order ----------
__global__ __launch_bounds__(256) void k_cast_w(const float* __restrict__ W,
                                                u16* __restrict__ wbf) {
    int idx = blockIdx.x * 256 + threadIdx.x;   // 2560 lane-slots
    if (idx >= 2560) return;
    int f = idx >> 6, lane = idx & 63;
    int q = lane >> 4, c = lane & 15;
    int kstep = f >> 2, nb = f & 3;
    u16* dst = wbf + (size_t)idx * 8;
#pragma unroll
    for (int j = 0; j < 8; j++) {
        int k = kstep * 32 + q * 8 + j;
        float v = (k < FDIM) ? W[k * DDIM + nb * 16 + c] : 0.f;
        dst[j] = f2bf(v);
    }
}

// ---------------- cast the 8 SAGE weight matrices to B-fragment order --------
__global__ __launch_bounds__(256) void k_cast_w8(
    const float* __restrict__ W0, const float* __restrict__ W1,
    const float* __restrict__ W2, const float* __restrict__ W3,
    const float* __restrict__ W4, const float* __restrict__ W5,
    const float* __restrict__ W6, const float* __restrict__ W7,
    u16* __restrict__ out) {
    int idx = blockIdx.x * 256 + threadIdx.x;   // 4096 slots
    if (idx >= 4096) return;
    int wm = idx >> 9;
    int s = idx & 511;
    int ks = s >> 8, nb = (s >> 6) & 3, lane = s & 63;
    int q = lane >> 4, c = lane & 15;
    const float* W;
    switch (wm) {
        case 0: W = W0; break; case 1: W = W1; break;
        case 2: W = W2; break; case 3: W = W3; break;
        case 4: W = W4; break; case 5: W = W5; break;
        case 6: W = W6; break; default: W = W7; break;
    }
    u16* dst = out + (size_t)idx * 8;
#pragma unroll
    for (int j = 0; j < 8; j++) {
        int row = ks * 32 + q * 8 + j;
        dst[j] = f2bf(W[row * DDIM + nb * 16 + c]);
    }
}

// ---------------- item linear via MFMA: xi = item_x @ W + b ------------------
__global__ __launch_bounds__(256) void k_item_lin2(const float* __restrict__ ix,
                                                   const u16* __restrict__ wbf,
                                                   const float* __restrict__ b,
                                                   u16* __restrict__ xi) {
    __shared__ __align__(16) u16 wl[40 * 64 * 8];   // 40960 B
    int tid = threadIdx.x;
    for (int i = tid; i < 2560; i += 256)
        ((f4v*)wl)[i] = ((const f4v*)wbf)[i];
    __syncthreads();

    int lane = tid & 63;
    int q = lane >> 4, c = lane & 15;
    float bv[4];
#pragma unroll
    for (int nb = 0; nb < 4; nb++) bv[nb] = b[nb * 16 + c];

    int w = blockIdx.x * 4 + (tid >> 6);
    int stride = gridDim.x * 4;
    const int NT = NIi / 16;   // 6250
    for (int t = w; t < NT; t += stride) {
        int row = t * 16 + c;
        const float* xr = ix + (size_t)row * FDIM;
        f4v acc[4];
#pragma unroll
        for (int nb = 0; nb < 4; nb++) {
            acc[nb][0] = bv[nb]; acc[nb][1] = bv[nb];
            acc[nb][2] = bv[nb]; acc[nb][3] = bv[nb];
        }
#pragma unroll
        for (int ks = 0; ks < 10; ks++) {
            s8v a;
            if (ks < 9 || q == 0) {
                float4 v0 = *(const float4*)(xr + ks * 32 + q * 8);
                float4 v1 = *(const float4*)(xr + ks * 32 + q * 8 + 4);
                a[0] = (short)f2bf(v0.x); a[1] = (short)f2bf(v0.y);
                a[2] = (short)f2bf(v0.z); a[3] = (short)f2bf(v0.w);
                a[4] = (short)f2bf(v1.x); a[5] = (short)f2bf(v1.y);
                a[6] = (short)f2bf(v1.z); a[7] = (short)f2bf(v1.w);
            } else {   // ks==9, q==1: k = 296..303, valid only 296..299
                float4 v0 = *(const float4*)(xr + 296);
                a[0] = (short)f2bf(v0.x); a[1] = (short)f2bf(v0.y);
                a[2] = (short)f2bf(v0.z); a[3] = (short)f2bf(v0.w);
                a[4] = 0; a[5] = 0; a[6] = 0; a[7] = 0;
            }
#pragma unroll
            for (int nb = 0; nb < 4; nb++) {
                s8v bb = *(const s8v*)(wl + ((size_t)(ks * 4 + nb) * 64 + lane) * 8);
                acc[nb] = __builtin_amdgcn_mfma_f32_16x16x32_bf16(a, bb, acc[nb], 0, 0, 0);
            }
        }
#pragma unroll
        for (int nb = 0; nb < 4; nb++)
#pragma unroll
            for (int r = 0; r < 4; r++)
                xi[(size_t)(t * 16 + q * 4 + r) * DDIM + nb * 16 + c] = f2bf(acc[nb][r]);
    }
}

// ---------------- CSR build: bucketed multisplit ------------------------------
__global__ __launch_bounds__(256) void k_hist(const int* __restrict__ src,
                                              const int* __restrict__ dst,
                                              int* __restrict__ hist) {
    __shared__ int h[NBT];
    int t = threadIdx.x;
    for (int c = t; c < NBT; c += 256) h[c] = 0;
    __syncthreads();
    int base = blockIdx.x * EPB;
    for (int k = 0; k < KPB; k++) {
        int e = base + k * 256 + t;
        if (e < NEe) {
            int s = src[e], d = dst[e];
            atomicAdd(&h[d >> BSZL_I], 1);
            atomicAdd(&h[NB_I + (s >> BSZL_U)], 1);
        }
    }
    __syncthreads();
    for (int c = t; c < NBT; c += 256) {
        int n = h[c];
        if (n) atomicAdd(&hist[c], n);
    }
}

__device__ __forceinline__ void scanN(const int* __restrict__ cnt, int n, int total,
                                      int* __restrict__ base, int* __restrict__ frontier,
                                      int* sb) {
    int t = threadIdx.x;
    int v[8]; int s = 0;
#pragma unroll
    for (int i = 0; i < 8; i++) {
        int idx = t * 8 + i;
        v[i] = (idx < n) ? cnt[idx] : 0;
        s += v[i];
    }
    sb[t] = s; __syncthreads();
    for (int o = 1; o < 256; o <<= 1) {
        int a = (t >= o) ? sb[t - o] : 0;
        __syncthreads();
        sb[t] += a;
        __syncthreads();
    }
    int run = sb[t] - s;
#pragma unroll
    for (int i = 0; i < 8; i++) {
        int idx = t * 8 + i;
        if (idx < n) { base[idx] = run; frontier[idx] = run; }
        run += v[i];
    }
    if (t == 0) base[n] = total;
    __syncthreads();
}

__global__ __launch_bounds__(256) void k_bucket_scan(const int* __restrict__ hist,
                                                     int* __restrict__ base_i, int* __restrict__ fr_i,
                                                     int* __restrict__ base_u, int* __restrict__ fr_u,
                                                     int* __restrict__ rpi, int* __restrict__ rpu) {
    __shared__ int sb[256];
    scanN(hist, NB_I, NEe, base_i, fr_i, sb);
    scanN(hist + NB_I, NB_U, NEe, base_u, fr_u, sb);
    if (threadIdx.x == 0) { rpi[NIi] = NEe; rpu[NUu] = NEe; }
}

__global__ __launch_bounds__(256) void k_scatter(const int* __restrict__ src,
                                                 const int* __restrict__ dst,
                                                 int* __restrict__ fr_i, int* __restrict__ fr_u,
                                                 unsigned* __restrict__ scat_i,
                                                 unsigned* __restrict__ scat_u) {
    __shared__ int h[NBT];
    int t = threadIdx.x;
    for (int c = t; c < NBT; c += 256) h[c] = 0;
    __syncthreads();
    int base = blockIdx.x * EPB;
    for (int k = 0; k < KPB; k++) {
        int e = base + k * 256 + t;
        if (e < NEe) {
            int s = src[e], d = dst[e];
            atomicAdd(&h[d >> BSZL_I], 1);
            atomicAdd(&h[NB_I + (s >> BSZL_U)], 1);
        }
    }
    __syncthreads();
    for (int c = t; c < NBT; c += 256) {
        int n = h[c];
        if (n) {
            int b = (c < NB_I) ? atomicAdd(&fr_i[c], n) : atomicAdd(&fr_u[c - NB_I], n);
            h[c] = b;
        }
    }
    __syncthreads();
    for (int k = 0; k < KPB; k++) {
        int e = base + k * 256 + t;
        if (e < NEe) {
            int s = src[e], d = dst[e];
            int p = atomicAdd(&h[d >> BSZL_I], 1);
            scat_i[p] = (unsigned)s | ((unsigned)(d & ((1 << BSZL_I) - 1)) << SH_I);
            int q = atomicAdd(&h[NB_I + (s >> BSZL_U)], 1);
            scat_u[q] = (unsigned)d | ((unsigned)(s & ((1 << BSZL_U) - 1)) << SH_U);
        }
    }
}

__global__ __launch_bounds__(256) void k_bfill(const unsigned* __restrict__ scat,
                                               const int* __restrict__ base,
                                               int* __restrict__ rp, int* __restrict__ col,
                                               int shift, int bszlog, int ntotal) {
    __shared__ int cnt[1024];
    __shared__ int pos[1024];
    __shared__ int sb[256];
    int b = blockIdx.x;
    int t = threadIdx.x;
    int e0 = base[b], e1 = base[b + 1];
    int node0 = b << bszlog;
    int bsz = 1 << bszlog;
    unsigned mask = (1u << shift) - 1u;

    for (int c = t; c < bsz; c += 256) cnt[c] = 0;
    __syncthreads();
    for (int e = e0 + t; e < e1; e += 256) {
        unsigned v = scat[e];
        atomicAdd(&cnt[v >> shift], 1);
    }
    __syncthreads();
    int per = bsz >> 8;   // 2 (item, bsz=512) or 4 (user, bsz=1024)
    int loc[4]; int ls = 0;
#pragma unroll
    for (int i = 0; i < 4; i++) {
        loc[i] = (i < per) ? cnt[t * per + i] : 0;
        ls += loc[i];
    }
    sb[t] = ls; __syncthreads();
    for (int o = 1; o < 256; o <<= 1) {
        int a = (t >= o) ? sb[t - o] : 0;
        __syncthreads();
        sb[t] += a;
        __syncthreads();
    }
    int run = e0 + sb[t] - ls;
#pragma unroll
    for (int i = 0; i < 4; i++) {
        if (i < per) {
            int idx = t * per + i;
            int node = node0 + idx;
            if (node < ntotal) rp[node] = run;
            pos[idx] = run;
            run += loc[i];
        }
    }
    __syncthreads();
    for (int e = e0 + t; e < e1; e += 256) {
        unsigned v = scat[e];
        int l = v >> shift;
        int p = atomicAdd(&pos[l], 1);
        col[p] = (int)(v & mask);
    }
}

// ---------------- degree counting-sort (64 bins) -----------------------------
__global__ __launch_bounds__(256) void k_dhist(const int* __restrict__ rp,
                                               int* __restrict__ hist, int n) {
    __shared__ int h[DBINS];
    int t = threadIdx.x;
    if (t < DBINS) h[t] = 0;
    __syncthreads();
    int base = blockIdx.x * 2048;
#pragma unroll
    for (int k = 0; k < 8; k++) {
        int i = base + k * 256 + t;
        if (i < n) {
            int d = rp[i + 1] - rp[i];
            atomicAdd(&h[min(d, DBINS - 1)], 1);
        }
    }
    __syncthreads();
    if (t < DBINS) { int v = h[t]; if (v) atomicAdd(&hist[t], v); }
}

// exclusive-scan both 64-bin histograms in place (128 threads = 2 waves)
__global__ void k_dscan2(int* __restrict__ hu, int* __restrict__ hi) {
    int t = threadIdx.x;
    int* h = (t < 64) ? hu : hi;
    int tt = t & 63;
    int v = h[tt];
    int s = v;
#pragma unroll
    for (int o = 1; o < 64; o <<= 1) {
        int a = __shfl_up(s, o);
        if (tt >= o) s += a;
    }
    h[tt] = s - v;   // exclusive prefix
}

__global__ __launch_bounds__(256) void k_dscatter(const int* __restrict__ rp,
                                                  int* __restrict__ bpos,
                                                  int* __restrict__ nsort,
                                                  int2* __restrict__ nmeta, int n) {
    __shared__ int h[DBINS];
    __shared__ int bb[DBINS];
    int t = threadIdx.x;
    if (t < DBINS) h[t] = 0;
    __syncthreads();
    int base = blockIdx.x * 2048;
    int d[8], s0[8];
#pragma unroll
    for (int k = 0; k < 8; k++) {
        int i = base + k * 256 + t;
        if (i < n) {
            int a = rp[i], b = rp[i + 1];
            s0[k] = a;
            d[k] = b - a;
            atomicAdd(&h[min(d[k], DBINS - 1)], 1);
        } else d[k] = -1;
    }
    __syncthreads();
    if (t < DBINS) {
        int v = h[t];
        bb[t] = v ? atomicAdd(&bpos[t], v) : 0;
        h[t] = 0;
    }
    __syncthreads();
#pragma unroll
    for (int k = 0; k < 8; k++) {
        if (d[k] >= 0) {
            int bin = min(d[k], DBINS - 1);
            int p = bb[bin] + atomicAdd(&h[bin], 1);
            nsort[p] = base + k * 256 + t;
            nmeta[p] = make_int2(s0[k], d[k]);
        }
    }
}

// ---------------- fused mean-agg + SAGE transform (pipelined) ----------------
__device__ __forceinline__ void acc_pair(float m, u4v v0, u4v v1,
                                         float* A, float* B) {
#pragma unroll
    for (int k = 0; k < 4; k++) {
        A[2 * k]     = fmaf(m, lo2f(v0[k]), A[2 * k]);
        A[2 * k + 1] = fmaf(m, hi2f(v0[k]), A[2 * k + 1]);
        B[2 * k]     = fmaf(m, lo2f(v1[k]), B[2 * k]);
        B[2 * k + 1] = fmaf(m, hi2f(v1[k]), B[2 * k + 1]);
    }
}

__global__ __launch_bounds__(256) void k_fused(const u16* __restrict__ feat,
                                               const u16* __restrict__ xf,
                                               const u16* __restrict__ wfrag,
                                               const float* __restrict__ bias,
                                               u16* __restrict__ out,
                                               const int* __restrict__ nsort,
                                               const int2* __restrict__ nmeta,
                                               const int* __restrict__ col,
                                               int ntiles, int relu) {
    __shared__ __align__(16) u16 wsh[8192];        // 16 KB weights
    __shared__ __align__(16) u16 csh[4][16][72];   // per-wave C-transpose, 9216 B
    int tid = threadIdx.x;
    for (int i = tid; i < 1024; i += 256)
        ((f4v*)wsh)[i] = ((const f4v*)wfrag)[i];
    __syncthreads();

    int lane = tid & 63;
    int q = lane >> 4, c = lane & 15;
    int wv = tid >> 6;
    int w = blockIdx.x * 4 + wv;
    int stride = gridDim.x * 4;
    float bv[4];
#pragma unroll
    for (int nb = 0; nb < 4; nb++) bv[nb] = bias[nb * 16 + c];

    u16 (*crow)[72] = csh[wv];
    int row0 = lane >> 3, c80 = lane & 7;   // epilogue read assignment
    const int idmax = ntiles * 16 - 1;

    if (w >= ntiles) return;

    // ---- pipeline prologue: state for first tile ----
    int idx0 = w * 16 + c;
    int node = nsort[idx0];
    int2 meta = nmeta[idx0];
    int s0 = meta.x, deg = meta.y;
    float inv = (deg > 0) ? 1.0f / (float)deg : 0.0f;
    int cc0 = col[min(s0,     EMAX)];
    int cc1 = col[min(s0 + 1, EMAX)];
    int cc2 = col[min(s0 + 2, EMAX)];
    int cc3 = col[min(s0 + 3, EMAX)];

    for (int t = w; t < ntiles; t += stride) {
        // issue next tile's node/meta early (latency covered by gather+MFMA)
        int idxN = min((t + stride) * 16 + c, idmax);
        int nodeN = nsort[idxN];
        int2 metaN = nmeta[idxN];

        // self fragments (consumed at MFMA, latency hidden by gather loop)
        const s8v* px = (const s8v*)(xf + (size_t)node * DDIM + q * 8);
        s8v x0 = px[0], x1 = px[4];

        float accA[8] = {0.f, 0.f, 0.f, 0.f, 0.f, 0.f, 0.f, 0.f};
        float accB[8] = {0.f, 0.f, 0.f, 0.f, 0.f, 0.f, 0.f, 0.f};

        // gather loop: current col group resident; prefetch next group under
        // the feat loads (only feat round-trip on the critical path)
        int g0 = cc0, g1 = cc1, g2 = cc2, g3 = cc3;
        for (int i = 0; ;) {
            int p0 = col[min(s0 + i + 4, EMAX)];
            int p1 = col[min(s0 + i + 5, EMAX)];
            int p2 = col[min(s0 + i + 6, EMAX)];
            int p3 = col[min(s0 + i + 7, EMAX)];
            float m0 = (i     < deg) ? inv : 0.f;
            float m1 = (i + 1 < deg) ? inv : 0.f;
            float m2 = (i + 2 < deg) ? inv : 0.f;
            float m3 = (i + 3 < deg) ? inv : 0.f;
            const u4v* f0 = (const u4v*)(feat + (size_t)g0 * DDIM + q * 8);
            const u4v* f1 = (const u4v*)(feat + (size_t)g1 * DDIM + q * 8);
            const u4v* f2 = (const u4v*)(feat + (size_t)g2 * DDIM + q * 8);
            const u4v* f3 = (const u4v*)(feat + (size_t)g3 * DDIM + q * 8);
            u4v a00 = f0[0], a01 = f0[4];
            u4v a10 = f1[0], a11 = f1[4];
            u4v a20 = f2[0], a21 = f2[4];
            u4v a30 = f3[0], a31 = f3[4];
            acc_pair(m0, a00, a01, accA, accB);
            acc_pair(m1, a10, a11, accA, accB);
            acc_pair(m2, a20, a21, accA, accB);
            acc_pair(m3, a30, a31, accA, accB);
            i += 4;
            if (!__any(i < deg)) break;
            g0 = p0; g1 = p1; g2 = p2; g3 = p3;
        }

        // issue NEXT tile's first col group now (covered by MFMA+epilogue)
        int s0N = metaN.x, degN = metaN.y;
        float invN = (degN > 0) ? 1.0f / (float)degN : 0.0f;
        cc0 = col[min(s0N,     EMAX)];
        cc1 = col[min(s0N + 1, EMAX)];
        cc2 = col[min(s0N + 2, EMAX)];
        cc3 = col[min(s0N + 3, EMAX)];

        // mean folded into masks; convert to A-fragments
        s8v a0, a1;
#pragma unroll
        for (int j = 0; j < 8; j++) {
            a0[j] = (short)f2bf(accA[j]);
            a1[j] = (short)f2bf(accB[j]);
        }

        f4v acc[4];
#pragma unroll
        for (int nb = 0; nb < 4; nb++) {
            acc[nb][0] = bv[nb]; acc[nb][1] = bv[nb];
            acc[nb][2] = bv[nb]; acc[nb][3] = bv[nb];
        }

        // launder LDS offset so weight ds_reads aren't hoisted into VGPRs
        unsigned lz = (unsigned)lane * 8u;
        asm volatile("" : "+v"(lz));
        const u16* wb = wsh + lz;
#pragma unroll
        for (int nb = 0; nb < 4; nb++) {
            s8v wl0 = *(const s8v*)(wb + nb * 512);            // Wl ks=0
            s8v wl1 = *(const s8v*)(wb + 2048 + nb * 512);     // Wl ks=1
            s8v wr0 = *(const s8v*)(wb + 4096 + nb * 512);     // Wr ks=0
            s8v wr1 = *(const s8v*)(wb + 6144 + nb * 512);     // Wr ks=1
            acc[nb] = __builtin_amdgcn_mfma_f32_16x16x32_bf16(a0, wl0, acc[nb], 0, 0, 0);
            acc[nb] = __builtin_amdgcn_mfma_f32_16x16x32_bf16(a1, wl1, acc[nb], 0, 0, 0);
            acc[nb] = __builtin_amdgcn_mfma_f32_16x16x32_bf16(x0, wr0, acc[nb], 0, 0, 0);
            acc[nb] = __builtin_amdgcn_mfma_f32_16x16x32_bf16(x1, wr1, acc[nb], 0, 0, 0);
        }

        // epilogue: per-wave LDS transpose -> full-line vector stores (no RFO)
#pragma unroll
        for (int nb = 0; nb < 4; nb++)
#pragma unroll
            for (int r = 0; r < 4; r++) {
                float v = acc[nb][r];
                if (relu) v = fmaxf(v, 0.f);
                crow[q * 4 + r][nb * 16 + c] = f2bf(v);
            }
        // same-wave LDS dep: compiler inserts lgkmcnt wait
        s8v v0 = *(const s8v*)&crow[row0][c80 * 8];
        s8v v1 = *(const s8v*)&crow[8 + row0][c80 * 8];
        int n0 = __shfl(node, row0);
        int n1 = __shfl(node, 8 + row0);
        *(s8v*)(out + (size_t)n0 * DDIM + c80 * 8) = v0;
        *(s8v*)(out + (size_t)n1 * DDIM + c80 * 8) = v1;

        // rotate pipeline state
        node = nodeN; s0 = s0N; deg = degN; inv = invN;
    }
}

// ---------------- final dot predictor (8 edges per wave, 16 B/lane) ----------
__global__ __launch_bounds__(256) void k_dot(const u16* __restrict__ hu,
                                             const u16* __restrict__ hi,
                                             const int* __restrict__ ls,
                                             const int* __restrict__ ld,
                                             float* __restrict__ out) {
    int lane = threadIdx.x & 63;
    int sub = lane >> 3, t8 = lane & 7;
    int w = blockIdx.x * 4 + (threadIdx.x >> 6);
    int stride = gridDim.x * 4;
    const int ngroups = ELl / 8;
    for (int g = w; g < ngroups; g += stride) {
        int e = g * 8 + sub;
        int u = ls[e], it = ld[e];
        s8v av = *(const s8v*)(hu + (size_t)u  * DDIM + t8 * 8);
        s8v bv = *(const s8v*)(hi + (size_t)it * DDIM + t8 * 8);
        float s = 0.f;
#pragma unroll
        for (int k = 0; k < 8; k++) s += bf2f((u16)av[k]) * bf2f((u16)bv[k]);
        s += __shfl_xor(s, 4);
        s += __shfl_xor(s, 2);
        s += __shfl_xor(s, 1);
        if (t8 == 0) out[e] = s;
    }
}

extern "C" void kernel_launch(void* const* d_in, const int* in_sizes, int n_in,
                              void* d_out, int out_size, void* d_ws, size_t ws_size,
                              hipStream_t stream) {
    const float* user_emb = (const float*)d_in[0];
    const float* item_x   = (const float*)d_in[1];
    const float* item_w   = (const float*)d_in[2];
    const float* item_b   = (const float*)d_in[3];
    const float* Wl1_ui = (const float*)d_in[4];
    const float* Wr1_ui = (const float*)d_in[5];
    const float* b1_ui  = (const float*)d_in[6];
    const float* Wl1_iu = (const float*)d_in[7];
    const float* Wr1_iu = (const float*)d_in[8];
    const float* b1_iu  = (const float*)d_in[9];
    const float* Wl2_ui = (const float*)d_in[10];
    const float* Wr2_ui = (const float*)d_in[11];
    const float* b2_ui  = (const float*)d_in[12];
    const float* Wl2_iu = (const float*)d_in[13];
    const float* Wr2_iu = (const float*)d_in[14];
    const float* b2_iu  = (const float*)d_in[15];
    const int* uid  = (const int*)d_in[16];
    const int* esrc = (const int*)d_in[17];
    const int* edst = (const int*)d_in[18];
    const int* lsrc = (const int*)d_in[19];
    const int* ldst = (const int*)d_in[20];
    float* out = (float*)d_out;

    char* ws = (char*)d_ws;
    size_t off = 0;
    auto alloc = [&](size_t bytes) -> void* {
        void* p = ws + off;
        off += (bytes + 255) & ~(size_t)255;
        return p;
    };
    u16* xu_b   = (u16*)alloc((size_t)NUu * DDIM * 2);
    u16* hu1_b  = (u16*)alloc((size_t)NUu * DDIM * 2);
    u16* hu2_b  = (u16*)alloc((size_t)NUu * DDIM * 2);
    u16* xi_b   = (u16*)alloc((size_t)NIi * DDIM * 2);
    u16* hi1_b  = (u16*)alloc((size_t)NIi * DDIM * 2);
    u16* hi2_b  = (u16*)alloc((size_t)NIi * DDIM * 2);
    int* coli = (int*)alloc((size_t)NEe * 4);
    int* colu = (int*)alloc((size_t)NEe * 4);
    int* rpi  = (int*)alloc((size_t)(NIi + 1) * 4);
    int* rpu  = (int*)alloc((size_t)(NUu + 1) * 4);
    int* hist   = (int*)alloc((size_t)NBT * 4);
    int* base_i = (int*)alloc((size_t)(NB_I + 1) * 4);
    int* base_u = (int*)alloc((size_t)(NB_U + 1) * 4);
    int* fr_i   = (int*)alloc((size_t)NB_I * 4);
    int* fr_u   = (int*)alloc((size_t)NB_U * 4);
    u16* wbf    = (u16*)alloc((size_t)40 * 64 * 8 * 2);   // item W, frag order
    u16* wfrag2 = (u16*)alloc((size_t)4 * 8192 * 2);      // 4 transforms x 16 KB
    int* nsort_i  = (int*)alloc((size_t)NIi * 4);
    int2* nmeta_i = (int2*)alloc((size_t)NIi * 8);
    int* nsort_u  = (int*)alloc((size_t)NUu * 4);
    int2* nmeta_u = (int2*)alloc((size_t)NUu * 8);
    int* dhist_i  = (int*)alloc((size_t)DBINS * 4);
    int* dhist_u  = (int*)alloc((size_t)DBINS * 4);
    // scatter buffers alias xu_b (16 MB < 64 MB): CSR build runs before k_cast_users
    unsigned* scat_i = (unsigned*)xu_b;
    unsigned* scat_u = (unsigned*)((char*)xu_b + (size_t)NEe * 4);

    // ---- CSR build (bucketed) ----
    hipMemsetAsync(hist, 0, (size_t)NBT * 4, stream);
    hipMemsetAsync(dhist_i, 0, (size_t)DBINS * 4, stream);
    hipMemsetAsync(dhist_u, 0, (size_t)DBINS * 4, stream);
    int nchunks = (NEe + EPB - 1) / EPB;   // 245
    k_hist<<<nchunks, 256, 0, stream>>>(esrc, edst, hist);
    k_bucket_scan<<<1, 256, 0, stream>>>(hist, base_i, fr_i, base_u, fr_u, rpi, rpu);
    k_scatter<<<nchunks, 256, 0, stream>>>(esrc, edst, fr_i, fr_u, scat_i, scat_u);
    k_bfill<<<NB_I, 256, 0, stream>>>(scat_i, base_i, rpi, coli, SH_I, BSZL_I, NIi);
    k_bfill<<<NB_U, 256, 0, stream>>>(scat_u, base_u, rpu, colu, SH_U, BSZL_U, NUu);

    // ---- degree sort (counting sort, 64 bins) ----
    int nci = (NIi + 2047) / 2048;   // 49
    int ncu = (NUu + 2047) / 2048;   // 245
    k_dhist<<<nci, 256, 0, stream>>>(rpi, dhist_i, NIi);
    k_dhist<<<ncu, 256, 0, stream>>>(rpu, dhist_u, NUu);
    k_dscan2<<<1, 128, 0, stream>>>(dhist_u, dhist_i);
    k_dscatter<<<nci, 256, 0, stream>>>(rpi, dhist_i, nsort_i, nmeta_i, NIi);
    k_dscatter<<<ncu, 256, 0, stream>>>(rpu, dhist_u, nsort_u, nmeta_u, NUu);

    // ---- input features (after CSR build: scat_* alias xu_b) ----
    k_cast_w<<<10, 256, 0, stream>>>(item_w, wbf);
    k_cast_w8<<<16, 256, 0, stream>>>(Wl1_ui, Wr1_ui, Wl1_iu, Wr1_iu,
                                      Wl2_ui, Wr2_ui, Wl2_iu, Wr2_iu, wfrag2);
    k_cast_users<<<NUu * 16 / 256, 256, 0, stream>>>(user_emb, uid, xu_b);
    k_item_lin2<<<1024, 256, 0, stream>>>(item_x, wbf, item_b, xi_b);

    const int NT_I = NIi / 16;   // 6250
    const int NT_U = NUu / 16;   // 31250

    // layer 1 (fused agg + transform, degree-sorted tiles, pipelined)
    k_fused<<<1536, 256, 0, stream>>>(xu_b, xi_b, wfrag2 + 0 * 8192, b1_ui,
                                      hi1_b, nsort_i, nmeta_i, coli, NT_I, 1);
    k_fused<<<1536, 256, 0, stream>>>(xi_b, xu_b, wfrag2 + 1 * 8192, b1_iu,
                                      hu1_b, nsort_u, nmeta_u, colu, NT_U, 1);
    // layer 2
    k_fused<<<1536, 256, 0, stream>>>(hu1_b, hi1_b, wfrag2 + 2 * 8192, b2_ui,
                                      hi2_b, nsort_i, nmeta_i, coli, NT_I, 0);
    k_fused<<<1536, 256, 0, stream>>>(hi1_b, hu1_b, wfrag2 + 3 * 8192, b2_iu,
                                      hu2_b, nsort_u, nmeta_u, colu, NT_U, 0);

    // predictor
    k_dot<<<2048, 256, 0, stream>>>(hu2_b, hi2_b, lsrc, ldst, out);
}